// Round 1
// baseline (255.335 us; speedup 1.0000x reference)
//
#include <hip/hip_runtime.h>
#include <stdint.h>

typedef unsigned short u16;
typedef float f32x4 __attribute__((ext_vector_type(4)));
typedef short sh8 __attribute__((ext_vector_type(8)));
typedef __bf16 bf16x8 __attribute__((ext_vector_type(8)));

#define DDIM 768
#define NHEAD 12
#define EDIM 64
#define SREAL 2000
#define SPAD 2048
#define NQ 2048

__device__ __forceinline__ u16 f2bf(float f) {
    unsigned u = __float_as_uint(f);
    return (u16)((u + 0x7fffu + ((u >> 16) & 1u)) >> 16);
}

__device__ __forceinline__ void async16(const void* g, void* l) {
    __builtin_amdgcn_global_load_lds(
        (const __attribute__((address_space(1))) void*)(const void*)g,
        (__attribute__((address_space(3))) void*)l, 16, 0, 0);
}

// ---------------- cast fp32 weights -> bf16 ----------------
__global__ __launch_bounds__(256) void castw_kernel(
    const float* __restrict__ Wq, const float* __restrict__ Wk, const float* __restrict__ Wv,
    u16* __restrict__ Wqb, u16* __restrict__ Wkb, u16* __restrict__ Wvb)
{
    int g = blockIdx.x * 256 + threadIdx.x;   // float4 index, total 3*147456
    const float* src; u16* dst; int idx;
    if (g < 147456)      { src = Wq; dst = Wqb; idx = g; }
    else if (g < 294912) { src = Wk; dst = Wkb; idx = g - 147456; }
    else                 { src = Wv; dst = Wvb; idx = g - 294912; }
    f32x4 a = ((const f32x4*)src)[idx];
    ushort4 o;
    o.x = f2bf(a[0]); o.y = f2bf(a[1]); o.z = f2bf(a[2]); o.w = f2bf(a[3]);
    ((ushort4*)dst)[idx] = o;
}

// ---------------- layernorm (fp32 in, bf16 out) ----------------
__global__ __launch_bounds__(256) void ln_kernel(
    const float* __restrict__ tgt, const float* __restrict__ keyb, const float* __restrict__ valb,
    const float* __restrict__ g_q, const float* __restrict__ b_q,
    const float* __restrict__ g_kv, const float* __restrict__ b_kv,
    u16* __restrict__ lnQ, u16* __restrict__ lnK, u16* __restrict__ lnV)
{
    int row = blockIdx.x * 4 + (threadIdx.x >> 6);   // 0..6143
    int l = threadIdx.x & 63;
    const float* src = nullptr; const float* gg; const float* bb; u16* dst;
    bool zero = false;
    if (row < 2048) {
        src = tgt + (size_t)row * DDIM; gg = g_q; bb = b_q; dst = lnQ + (size_t)row * DDIM;
    } else if (row < 4096) {
        int r = row - 2048; gg = g_kv; bb = b_kv; dst = lnK + (size_t)r * DDIM;
        if (r < SREAL) src = keyb + (size_t)r * DDIM; else zero = true;
    } else {
        int r = row - 4096; gg = g_kv; bb = b_kv; dst = lnV + (size_t)r * DDIM;
        if (r < SREAL) src = valb + (size_t)r * DDIM; else zero = true;
    }
    if (zero) {
        ushort4 z; z.x = 0; z.y = 0; z.z = 0; z.w = 0;
#pragma unroll
        for (int i = 0; i < 3; i++) ((ushort4*)dst)[l + 64 * i] = z;
        return;
    }
    f32x4 a[3];
#pragma unroll
    for (int i = 0; i < 3; i++) a[i] = ((const f32x4*)src)[l + 64 * i];
    float s = 0.f;
#pragma unroll
    for (int i = 0; i < 3; i++) { s += a[i][0] + a[i][1] + a[i][2] + a[i][3]; }
#pragma unroll
    for (int m = 1; m < 64; m <<= 1) s += __shfl_xor(s, m, 64);
    float mean = s * (1.f / 768.f);
    float v = 0.f;
#pragma unroll
    for (int i = 0; i < 3; i++)
#pragma unroll
        for (int j = 0; j < 4; j++) { float d = a[i][j] - mean; v += d * d; }
#pragma unroll
    for (int m = 1; m < 64; m <<= 1) v += __shfl_xor(v, m, 64);
    float rstd = rsqrtf(v * (1.f / 768.f) + 1e-5f);
#pragma unroll
    for (int i = 0; i < 3; i++) {
        f32x4 g4 = ((const f32x4*)gg)[l + 64 * i];
        f32x4 b4 = ((const f32x4*)bb)[l + 64 * i];
        ushort4 o;
        o.x = f2bf((a[i][0] - mean) * rstd * g4[0] + b4[0]);
        o.y = f2bf((a[i][1] - mean) * rstd * g4[1] + b4[1]);
        o.z = f2bf((a[i][2] - mean) * rstd * g4[2] + b4[2]);
        o.w = f2bf((a[i][3] - mean) * rstd * g4[3] + b4[3]);
        ((ushort4*)dst)[l + 64 * i] = o;
    }
}

// ---------------- batched projection GEMM: C = A(M,768) @ W(768,768)^T + bias, bf16 out ----------------
// 128x128 tile, BK=64, m97 structure. blockIdx.z selects {Q,K,V}.
__global__ __launch_bounds__(256) void proj_kernel(
    const u16* __restrict__ lnQ, const u16* __restrict__ lnK, const u16* __restrict__ lnV,
    const u16* __restrict__ Wqb, const u16* __restrict__ Wkb, const u16* __restrict__ Wvb,
    const float* __restrict__ bq, const float* __restrict__ bk, const float* __restrict__ bv,
    u16* __restrict__ Qm, u16* __restrict__ Km, u16* __restrict__ Vm)
{
    __shared__ u16 Ash[128 * 64];
    __shared__ u16 Bsh[128 * 64];
    const u16* A; const u16* W; const float* bias; u16* out; int Mact;
    int z = blockIdx.z;
    if (z == 0)      { A = lnQ; W = Wqb; bias = bq; out = Qm; Mact = 2048; }
    else if (z == 1) { A = lnK; W = Wkb; bias = bk; out = Km; Mact = SREAL; }
    else             { A = lnV; W = Wvb; bias = bv; out = Vm; Mact = SREAL; }
    int n0 = blockIdx.x * 128, m0 = blockIdx.y * 128;
    int t = threadIdx.x, l = t & 63, quad = l >> 4, c16 = l & 15;
    int wv = t >> 6, wm = wv >> 1, wn = wv & 1;

    f32x4 acc[4][4];
    f32x4 zz = {0.f, 0.f, 0.f, 0.f};
#pragma unroll
    for (int mi = 0; mi < 4; mi++)
#pragma unroll
        for (int ni = 0; ni < 4; ni++) acc[mi][ni] = zz;

    for (int kt = 0; kt < 12; kt++) {
        int k0 = kt * 64;
#pragma unroll
        for (int i = 0; i < 4; i++) {
            int ch = i * 256 + t;
            int r = ch >> 3, c8 = ch & 7;
            async16(A + (size_t)(m0 + r) * DDIM + k0 + c8 * 8, (char*)Ash + ch * 16);
            async16(W + (size_t)(n0 + r) * DDIM + k0 + c8 * 8, (char*)Bsh + ch * 16);
        }
        __syncthreads();
#pragma unroll
        for (int kk = 0; kk < 2; kk++) {
            bf16x8 a[4], b[4];
#pragma unroll
            for (int mi = 0; mi < 4; mi++)
                a[mi] = *(const bf16x8*)((const char*)Ash + ((wm * 64 + mi * 16 + c16) * 64 + kk * 32 + quad * 8) * 2);
#pragma unroll
            for (int ni = 0; ni < 4; ni++)
                b[ni] = *(const bf16x8*)((const char*)Bsh + ((wn * 64 + ni * 16 + c16) * 64 + kk * 32 + quad * 8) * 2);
#pragma unroll
            for (int mi = 0; mi < 4; mi++)
#pragma unroll
                for (int ni = 0; ni < 4; ni++)
                    acc[mi][ni] = __builtin_amdgcn_mfma_f32_16x16x32_bf16(a[mi], b[ni], acc[mi][ni], 0, 0, 0);
        }
        __syncthreads();
    }
#pragma unroll
    for (int mi = 0; mi < 4; mi++)
#pragma unroll
        for (int ni = 0; ni < 4; ni++) {
            int n = n0 + wn * 64 + ni * 16 + c16;
            float bval = bias[n];
#pragma unroll
            for (int r = 0; r < 4; r++) {
                int m = m0 + wm * 64 + mi * 16 + quad * 4 + r;
                float val = (m < Mact) ? (acc[mi][ni][r] + bval) : 0.f;
                out[(size_t)m * DDIM + n] = f2bf(val);
            }
        }
}

// ---------------- flash attention + mean-pool over TQ ----------------
// grid (16 q-tiles of 128, 12 heads), 256 threads. Per wave: 32 q rows.
__global__ __launch_bounds__(256) void attn_kernel(
    const u16* __restrict__ Qm, const u16* __restrict__ Km, const u16* __restrict__ Vm,
    const int* __restrict__ bank_mask, float* __restrict__ pooled)
{
    __shared__ u16 Pl[128 * 128];     // 32KB; first 16KB doubles as K-chunk staging
    __shared__ u16 Vt[64 * 136];      // V chunk transposed [e][s], padded rows
    __shared__ float mk[128];
    int h = blockIdx.y, q0 = blockIdx.x * 128;
    int t = threadIdx.x, w = t >> 6, l = t & 63, quad = l >> 4, c16 = l & 15;

    bf16x8 qf[2][2];
#pragma unroll
    for (int mi = 0; mi < 2; mi++)
#pragma unroll
        for (int kk = 0; kk < 2; kk++) {
            int row = q0 + w * 32 + mi * 16 + c16;
            qf[mi][kk] = *(const bf16x8*)(Qm + (size_t)row * DDIM + h * EDIM + kk * 32 + quad * 8);
        }

    f32x4 zz = {0.f, 0.f, 0.f, 0.f};
    f32x4 of[2][4];
    float mst[2][4], lst[2][4];
#pragma unroll
    for (int mi = 0; mi < 2; mi++) {
#pragma unroll
        for (int nei = 0; nei < 4; nei++) of[mi][nei] = zz;
#pragma unroll
        for (int r = 0; r < 4; r++) { mst[mi][r] = -3e38f; lst[mi][r] = 0.f; }
    }
    const float scale = 0.125f;

    for (int sc = 0; sc < 16; sc++) {
        int s0 = sc * 128;
        // stage K chunk (into Pl base) via global_load_lds
#pragma unroll
        for (int i = 0; i < 4; i++) {
            int ch = i * 256 + t;
            int r = ch >> 3, c8 = ch & 7;
            async16(Km + (size_t)(s0 + r) * DDIM + h * EDIM + c8 * 8, (char*)Pl + ch * 16);
        }
        // stage V chunk transposed
        {
            int sl = t >> 1, e0 = (t & 1) * 32;
            const u16* vsrc = Vm + (size_t)(s0 + sl) * DDIM + h * EDIM + e0;
#pragma unroll
            for (int j4 = 0; j4 < 4; j4++) {
                sh8 v = *(const sh8*)(vsrc + j4 * 8);
#pragma unroll
                for (int jj = 0; jj < 8; jj++)
                    Vt[(e0 + j4 * 8 + jj) * 136 + sl] = (u16)v[jj];
            }
        }
        if (t < 128) {
            int s = s0 + t;
            mk[t] = (s < SREAL && bank_mask[s] != 0) ? 0.f : -1e30f;
        }
        __syncthreads();   // staging visible (drains async loads)

        // QK^T
        f32x4 sacc[2][8];
#pragma unroll
        for (int mi = 0; mi < 2; mi++)
#pragma unroll
            for (int ni = 0; ni < 8; ni++) sacc[mi][ni] = zz;
#pragma unroll
        for (int kk = 0; kk < 2; kk++) {
            bf16x8 kb[8];
#pragma unroll
            for (int ni = 0; ni < 8; ni++)
                kb[ni] = *(const bf16x8*)((const char*)Pl + ((ni * 16 + c16) * 64 + kk * 32 + quad * 8) * 2);
#pragma unroll
            for (int mi = 0; mi < 2; mi++)
#pragma unroll
                for (int ni = 0; ni < 8; ni++)
                    sacc[mi][ni] = __builtin_amdgcn_mfma_f32_16x16x32_bf16(qf[mi][kk], kb[ni], sacc[mi][ni], 0, 0, 0);
        }
        float mload[8];
#pragma unroll
        for (int ni = 0; ni < 8; ni++) mload[ni] = mk[ni * 16 + c16];

        // online softmax (P values left in sacc)
#pragma unroll
        for (int mi = 0; mi < 2; mi++)
#pragma unroll
            for (int r = 0; r < 4; r++) {
                float sv[8];
                float rm = -3e38f;
#pragma unroll
                for (int ni = 0; ni < 8; ni++) {
                    sv[ni] = sacc[mi][ni][r] * scale + mload[ni];
                    rm = fmaxf(rm, sv[ni]);
                }
#pragma unroll
                for (int mm = 1; mm < 16; mm <<= 1) rm = fmaxf(rm, __shfl_xor(rm, mm, 64));
                float mnew = fmaxf(mst[mi][r], rm);
                float alpha = __expf(mst[mi][r] - mnew);
                float rs = 0.f;
#pragma unroll
                for (int ni = 0; ni < 8; ni++) {
                    float p = __expf(sv[ni] - mnew);
                    rs += p;
                    sacc[mi][ni][r] = p;
                }
#pragma unroll
                for (int mm = 1; mm < 16; mm <<= 1) rs += __shfl_xor(rs, mm, 64);
                lst[mi][r] = lst[mi][r] * alpha + rs;
                mst[mi][r] = mnew;
#pragma unroll
                for (int nei = 0; nei < 4; nei++) of[mi][nei][r] *= alpha;
            }
        __syncthreads();   // all waves done reading K region before P overwrites it

        // write P (bf16) into Pl
#pragma unroll
        for (int mi = 0; mi < 2; mi++)
#pragma unroll
            for (int ni = 0; ni < 8; ni++)
#pragma unroll
                for (int r = 0; r < 4; r++) {
                    int prow = w * 32 + mi * 16 + quad * 4 + r;
                    Pl[prow * 128 + ni * 16 + c16] = f2bf(sacc[mi][ni][r]);
                }

        // O += P @ V  (each wave consumes its own P rows)
#pragma unroll
        for (int kk = 0; kk < 4; kk++) {
            bf16x8 pa[2], vb[4];
#pragma unroll
            for (int mi = 0; mi < 2; mi++)
                pa[mi] = *(const bf16x8*)((const char*)Pl + ((w * 32 + mi * 16 + c16) * 128 + kk * 32 + quad * 8) * 2);
#pragma unroll
            for (int nei = 0; nei < 4; nei++)
                vb[nei] = *(const bf16x8*)((const char*)Vt + ((nei * 16 + c16) * 136 + kk * 32 + quad * 8) * 2);
#pragma unroll
            for (int mi = 0; mi < 2; mi++)
#pragma unroll
                for (int nei = 0; nei < 4; nei++)
                    of[mi][nei] = __builtin_amdgcn_mfma_f32_16x16x32_bf16(pa[mi], vb[nei], of[mi][nei], 0, 0, 0);
        }
        __syncthreads();   // Vt/Pl reads done before next chunk's staging
    }

    // normalize, mean-pool over TQ=8, write pooled (256 x 768) fp32
#pragma unroll
    for (int mi = 0; mi < 2; mi++)
#pragma unroll
        for (int nei = 0; nei < 4; nei++) {
            float s4 = 0.f;
#pragma unroll
            for (int r = 0; r < 4; r++) s4 += of[mi][nei][r] / lst[mi][r];
            float s8 = s4 + __shfl_xor(s4, 16, 64);
            if ((quad & 1) == 0) {
                int g = (q0 >> 3) + w * 4 + mi * 2 + (quad >> 1);
                pooled[(size_t)g * DDIM + h * EDIM + nei * 16 + c16] = s8 * 0.125f;
            }
        }
}

// ---------------- init d_out with bias ----------------
__global__ __launch_bounds__(256) void bias_init_kernel(const float* __restrict__ bo, float* __restrict__ y)
{
    int f = blockIdx.x * 256 + threadIdx.x;   // 49152 float4s
    int c4 = f % 192;
    ((f32x4*)y)[f] = ((const f32x4*)bo)[c4];
}

// ---------------- final fp32 GEMM y += pooled(256,768) @ Wo(768,768)^T, split-K + atomics ----------------
__global__ __launch_bounds__(256) void wo_kernel(
    const float* __restrict__ pooled, const float* __restrict__ Wo, float* __restrict__ y)
{
    __shared__ float As[64 * 65];
    int m0 = blockIdx.x * 64, n0 = blockIdx.y * 128, k0 = blockIdx.z * 64;
    int t = threadIdx.x;
#pragma unroll
    for (int i = 0; i < 16; i++) {
        int f = i * 256 + t;
        int r = f >> 6, c = f & 63;
        As[r * 65 + c] = pooled[(size_t)(m0 + r) * DDIM + k0 + c];
    }
    __syncthreads();
    int tx = t & 31, my = t >> 5;
    float acc[8][4];
#pragma unroll
    for (int r = 0; r < 8; r++)
#pragma unroll
        for (int j = 0; j < 4; j++) acc[r][j] = 0.f;
    for (int kq = 0; kq < 16; kq++) {
        f32x4 bj[4];
#pragma unroll
        for (int j = 0; j < 4; j++)
            bj[j] = *(const f32x4*)(Wo + (size_t)(n0 + tx * 4 + j) * DDIM + k0 + kq * 4);
#pragma unroll
        for (int jj = 0; jj < 4; jj++) {
            int k = kq * 4 + jj;
            float a8[8];
#pragma unroll
            for (int r = 0; r < 8; r++) a8[r] = As[(my * 8 + r) * 65 + k];
#pragma unroll
            for (int r = 0; r < 8; r++)
#pragma unroll
                for (int j = 0; j < 4; j++) acc[r][j] += a8[r] * bj[j][jj];
        }
    }
#pragma unroll
    for (int r = 0; r < 8; r++)
#pragma unroll
        for (int j = 0; j < 4; j++)
            atomicAdd(&y[(size_t)(m0 + my * 8 + r) * DDIM + n0 + tx * 4 + j], acc[r][j]);
}

extern "C" void kernel_launch(void* const* d_in, const int* in_sizes, int n_in,
                              void* d_out, int out_size, void* d_ws, size_t ws_size,
                              hipStream_t stream)
{
    const float* tgt     = (const float*)d_in[0];
    const float* keyb    = (const float*)d_in[1];
    const float* valb    = (const float*)d_in[2];
    const int*   mask    = (const int*)d_in[3];
    const float* Wq      = (const float*)d_in[4];
    const float* bq      = (const float*)d_in[5];
    const float* Wk      = (const float*)d_in[6];
    const float* bk      = (const float*)d_in[7];
    const float* Wv      = (const float*)d_in[8];
    const float* bv      = (const float*)d_in[9];
    const float* Wo      = (const float*)d_in[10];
    const float* bo      = (const float*)d_in[11];
    const float* g_q     = (const float*)d_in[12];
    const float* beta_q  = (const float*)d_in[13];
    const float* g_kv    = (const float*)d_in[14];
    const float* beta_kv = (const float*)d_in[15];
    float* y = (float*)d_out;

    char* ws = (char*)d_ws;
    u16* lnQ = (u16*)(ws + 0);
    u16* lnK = (u16*)(ws + 3145728);
    u16* lnV = (u16*)(ws + 6291456);
    u16* Wqb = (u16*)(ws + 9437184);
    u16* Wkb = (u16*)(ws + 10616832);
    u16* Wvb = (u16*)(ws + 11796480);
    u16* Qm  = (u16*)(ws + 12976128);
    u16* Km  = (u16*)(ws + 16121856);
    u16* Vm  = (u16*)(ws + 19267584);
    float* pooled = (float*)(ws + 22413312);

    hipLaunchKernelGGL(castw_kernel, dim3(1728), dim3(256), 0, stream,
                       Wq, Wk, Wv, Wqb, Wkb, Wvb);
    hipLaunchKernelGGL(ln_kernel, dim3(1536), dim3(256), 0, stream,
                       tgt, keyb, valb, g_q, beta_q, g_kv, beta_kv, lnQ, lnK, lnV);
    hipLaunchKernelGGL(proj_kernel, dim3(6, 16, 3), dim3(256), 0, stream,
                       lnQ, lnK, lnV, Wqb, Wkb, Wvb, bq, bk, bv, Qm, Km, Vm);
    hipLaunchKernelGGL(attn_kernel, dim3(16, 12), dim3(256), 0, stream,
                       Qm, Km, Vm, mask, pooled);
    hipLaunchKernelGGL(bias_init_kernel, dim3(192), dim3(256), 0, stream, bo, y);
    hipLaunchKernelGGL(wo_kernel, dim3(4, 6, 12), dim3(256), 0, stream,
                       pooled, Wo, y);
}

// Round 2
// 252.663 us; speedup vs baseline: 1.0106x; 1.0106x over previous
//
#include <hip/hip_runtime.h>
#include <stdint.h>

typedef unsigned short u16;
typedef float f32x4 __attribute__((ext_vector_type(4)));
typedef __bf16 bf16x8 __attribute__((ext_vector_type(8)));

#define DDIM 768
#define NHEAD 12
#define EDIM 64
#define SREAL 2000
#define SPAD 2048
#define NQ 2048
#define NSPLIT 4

__device__ __forceinline__ u16 f2bf(float f) {
    unsigned u = __float_as_uint(f);
    return (u16)((u + 0x7fffu + ((u >> 16) & 1u)) >> 16);
}

__device__ __forceinline__ void async16(const void* g, void* l) {
    __builtin_amdgcn_global_load_lds(
        (const __attribute__((address_space(1))) void*)(const void*)g,
        (__attribute__((address_space(3))) void*)l, 16, 0, 0);
}

// ---------------- cast fp32 weights -> bf16 ----------------
__global__ __launch_bounds__(256) void castw_kernel(
    const float* __restrict__ Wq, const float* __restrict__ Wk, const float* __restrict__ Wv,
    u16* __restrict__ Wqb, u16* __restrict__ Wkb, u16* __restrict__ Wvb)
{
    int g = blockIdx.x * 256 + threadIdx.x;   // float4 index, total 3*147456
    const float* src; u16* dst; int idx;
    if (g < 147456)      { src = Wq; dst = Wqb; idx = g; }
    else if (g < 294912) { src = Wk; dst = Wkb; idx = g - 147456; }
    else                 { src = Wv; dst = Wvb; idx = g - 294912; }
    f32x4 a = ((const f32x4*)src)[idx];
    ushort4 o;
    o.x = f2bf(a[0]); o.y = f2bf(a[1]); o.z = f2bf(a[2]); o.w = f2bf(a[3]);
    ((ushort4*)dst)[idx] = o;
}

// ---------------- layernorm (fp32 in, bf16 out) ----------------
__global__ __launch_bounds__(256) void ln_kernel(
    const float* __restrict__ tgt, const float* __restrict__ keyb, const float* __restrict__ valb,
    const float* __restrict__ g_q, const float* __restrict__ b_q,
    const float* __restrict__ g_kv, const float* __restrict__ b_kv,
    u16* __restrict__ lnQ, u16* __restrict__ lnK, u16* __restrict__ lnV)
{
    int row = blockIdx.x * 4 + (threadIdx.x >> 6);   // 0..6143
    int l = threadIdx.x & 63;
    const float* src = nullptr; const float* gg; const float* bb; u16* dst;
    bool zero = false;
    if (row < 2048) {
        src = tgt + (size_t)row * DDIM; gg = g_q; bb = b_q; dst = lnQ + (size_t)row * DDIM;
    } else if (row < 4096) {
        int r = row - 2048; gg = g_kv; bb = b_kv; dst = lnK + (size_t)r * DDIM;
        if (r < SREAL) src = keyb + (size_t)r * DDIM; else zero = true;
    } else {
        int r = row - 4096; gg = g_kv; bb = b_kv; dst = lnV + (size_t)r * DDIM;
        if (r < SREAL) src = valb + (size_t)r * DDIM; else zero = true;
    }
    if (zero) {
        ushort4 z; z.x = 0; z.y = 0; z.z = 0; z.w = 0;
#pragma unroll
        for (int i = 0; i < 3; i++) ((ushort4*)dst)[l + 64 * i] = z;
        return;
    }
    f32x4 a[3];
#pragma unroll
    for (int i = 0; i < 3; i++) a[i] = ((const f32x4*)src)[l + 64 * i];
    float s = 0.f;
#pragma unroll
    for (int i = 0; i < 3; i++) { s += a[i][0] + a[i][1] + a[i][2] + a[i][3]; }
#pragma unroll
    for (int m = 1; m < 64; m <<= 1) s += __shfl_xor(s, m, 64);
    float mean = s * (1.f / 768.f);
    float v = 0.f;
#pragma unroll
    for (int i = 0; i < 3; i++)
#pragma unroll
        for (int j = 0; j < 4; j++) { float d = a[i][j] - mean; v += d * d; }
#pragma unroll
    for (int m = 1; m < 64; m <<= 1) v += __shfl_xor(v, m, 64);
    float rstd = rsqrtf(v * (1.f / 768.f) + 1e-5f);
#pragma unroll
    for (int i = 0; i < 3; i++) {
        f32x4 g4 = ((const f32x4*)gg)[l + 64 * i];
        f32x4 b4 = ((const f32x4*)bb)[l + 64 * i];
        ushort4 o;
        o.x = f2bf((a[i][0] - mean) * rstd * g4[0] + b4[0]);
        o.y = f2bf((a[i][1] - mean) * rstd * g4[1] + b4[1]);
        o.z = f2bf((a[i][2] - mean) * rstd * g4[2] + b4[2]);
        o.w = f2bf((a[i][3] - mean) * rstd * g4[3] + b4[3]);
        ((ushort4*)dst)[l + 64 * i] = o;
    }
}

// ---------------- batched projection GEMM: C = A(M,768) @ W(768,768)^T + bias ----------------
// 128x128 tile, BK=128 (6 k-iters), XOR-swizzled LDS. z=2 (V) writes transposed [n][m].
__global__ __launch_bounds__(256) void proj_kernel(
    const u16* __restrict__ lnQ, const u16* __restrict__ lnK, const u16* __restrict__ lnV,
    const u16* __restrict__ Wqb, const u16* __restrict__ Wkb, const u16* __restrict__ Wvb,
    const float* __restrict__ bq, const float* __restrict__ bk, const float* __restrict__ bv,
    u16* __restrict__ Qm, u16* __restrict__ Km, u16* __restrict__ VmT)
{
    __shared__ u16 Ash[128 * 128];
    __shared__ u16 Bsh[128 * 128];
    const u16* A; const u16* W; const float* bias; int z = blockIdx.z;
    if (z == 0)      { A = lnQ; W = Wqb; bias = bq; }
    else if (z == 1) { A = lnK; W = Wkb; bias = bk; }
    else             { A = lnV; W = Wvb; bias = bv; }
    int n0 = blockIdx.x * 128, m0 = blockIdx.y * 128;
    int t = threadIdx.x, l = t & 63, quad = l >> 4, c16 = l & 15;
    int wv = t >> 6, wm = wv >> 1, wn = wv & 1;

    f32x4 acc[4][4];
    f32x4 zz = {0.f, 0.f, 0.f, 0.f};
#pragma unroll
    for (int mi = 0; mi < 4; mi++)
#pragma unroll
        for (int ni = 0; ni < 4; ni++) acc[mi][ni] = zz;

    for (int kt = 0; kt < 6; kt++) {
        int k0 = kt * 128;
#pragma unroll
        for (int i = 0; i < 8; i++) {
            int ch = i * 256 + t;
            int r = ch >> 4, pc = ch & 15, jc = pc ^ (r & 15);
            async16(A + (size_t)(m0 + r) * DDIM + k0 + jc * 8, (char*)Ash + ch * 16);
            async16(W + (size_t)(n0 + r) * DDIM + k0 + jc * 8, (char*)Bsh + ch * 16);
        }
        __syncthreads();
#pragma unroll
        for (int kk = 0; kk < 4; kk++) {
            bf16x8 a[4], b[4];
#pragma unroll
            for (int mi = 0; mi < 4; mi++) {
                int row = wm * 64 + mi * 16 + c16;
                int p = (kk * 4 + quad) ^ c16;
                a[mi] = *(const bf16x8*)(Ash + row * 128 + p * 8);
            }
#pragma unroll
            for (int ni = 0; ni < 4; ni++) {
                int row = wn * 64 + ni * 16 + c16;
                int p = (kk * 4 + quad) ^ c16;
                b[ni] = *(const bf16x8*)(Bsh + row * 128 + p * 8);
            }
#pragma unroll
            for (int mi = 0; mi < 4; mi++)
#pragma unroll
                for (int ni = 0; ni < 4; ni++)
                    acc[mi][ni] = __builtin_amdgcn_mfma_f32_16x16x32_bf16(a[mi], b[ni], acc[mi][ni], 0, 0, 0);
        }
        __syncthreads();
    }
    if (z < 2) {
        u16* out = (z == 0) ? Qm : Km;
        int Mact = (z == 0) ? NQ : SREAL;
#pragma unroll
        for (int mi = 0; mi < 4; mi++)
#pragma unroll
            for (int ni = 0; ni < 4; ni++) {
                int n = n0 + wn * 64 + ni * 16 + c16;
                float bval = bias[n];
#pragma unroll
                for (int r = 0; r < 4; r++) {
                    int m = m0 + wm * 64 + mi * 16 + quad * 4 + r;
                    float val = (m < Mact) ? (acc[mi][ni][r] + bval) : 0.f;
                    out[(size_t)m * DDIM + n] = f2bf(val);
                }
            }
    } else {
        // V: write transposed [n (768)][m (2048)], zero pad rows m>=2000
#pragma unroll
        for (int mi = 0; mi < 4; mi++)
#pragma unroll
            for (int ni = 0; ni < 4; ni++) {
                int n = n0 + wn * 64 + ni * 16 + c16;
                float bval = bias[n];
                int mbase = m0 + wm * 64 + mi * 16 + quad * 4;
                ushort4 o;
                o.x = (mbase + 0 < SREAL) ? f2bf(acc[mi][ni][0] + bval) : (u16)0;
                o.y = (mbase + 1 < SREAL) ? f2bf(acc[mi][ni][1] + bval) : (u16)0;
                o.z = (mbase + 2 < SREAL) ? f2bf(acc[mi][ni][2] + bval) : (u16)0;
                o.w = (mbase + 3 < SREAL) ? f2bf(acc[mi][ni][3] + bval) : (u16)0;
                *(ushort4*)(VmT + (size_t)n * SPAD + mbase) = o;
            }
    }
}

// ---------------- split-S flash attention ----------------
// grid (32 q-tiles of 64, 12 heads, 4 s-parts of 512), 256 threads (4 waves x 16 q-rows).
__global__ __launch_bounds__(256, 4) void attn_kernel(
    const u16* __restrict__ Qm, const u16* __restrict__ Km, const u16* __restrict__ VmT,
    const int* __restrict__ bank_mask,
    float* __restrict__ Opart, float* __restrict__ Mpart, float* __restrict__ Lpart)
{
    __shared__ u16 KP[128 * 64];   // K chunk [128 s][64 e] -> reused as P [64 q][128 s]
    __shared__ u16 Vt[64 * 128];   // [e][s], XOR-swizzled
    __shared__ float mk[128];
    int h = blockIdx.y, q0 = blockIdx.x * 64, sp = blockIdx.z;
    int t = threadIdx.x, w = t >> 6, l = t & 63, quad = l >> 4, c16 = l & 15;

    bf16x8 qf[2];
#pragma unroll
    for (int kk = 0; kk < 2; kk++) {
        int row = q0 + w * 16 + c16;
        qf[kk] = *(const bf16x8*)(Qm + (size_t)row * DDIM + h * EDIM + kk * 32 + quad * 8);
    }

    f32x4 zz = {0.f, 0.f, 0.f, 0.f};
    f32x4 of[4];
    float mst[4], lst[4];
#pragma unroll
    for (int nei = 0; nei < 4; nei++) of[nei] = zz;
#pragma unroll
    for (int r = 0; r < 4; r++) { mst[r] = -3e38f; lst[r] = 0.f; }
    const float scale = 0.125f;

    for (int sc = 0; sc < 4; sc++) {
        int s0 = sp * 512 + sc * 128;
        // stage K chunk [128][64] swizzled
#pragma unroll
        for (int i = 0; i < 4; i++) {
            int ch = i * 256 + t;
            int r = ch >> 3, pc = ch & 7, jc = pc ^ (r & 7);
            async16(Km + (size_t)(s0 + r) * DDIM + h * EDIM + jc * 8, (char*)KP + ch * 16);
        }
        // stage V^T chunk [64 e][128 s] swizzled
#pragma unroll
        for (int i = 0; i < 4; i++) {
            int ch = i * 256 + t;
            int e = ch >> 4, pc = ch & 15, jc = pc ^ (e & 15);
            async16(VmT + (size_t)(h * EDIM + e) * SPAD + s0 + jc * 8, (char*)Vt + ch * 16);
        }
        if (t < 128) {
            int s = s0 + t;
            mk[t] = (s < SREAL && bank_mask[s] != 0) ? 0.f : -1e30f;
        }
        __syncthreads();

        // QK^T: wave's 16 q-rows x 128 s-cols
        f32x4 sacc[8];
#pragma unroll
        for (int ni = 0; ni < 8; ni++) sacc[ni] = zz;
#pragma unroll
        for (int kk = 0; kk < 2; kk++) {
            bf16x8 kb[8];
#pragma unroll
            for (int ni = 0; ni < 8; ni++) {
                int row = ni * 16 + c16;
                int p = (kk * 4 + quad) ^ (row & 7);
                kb[ni] = *(const bf16x8*)(KP + row * 64 + p * 8);
            }
#pragma unroll
            for (int ni = 0; ni < 8; ni++)
                sacc[ni] = __builtin_amdgcn_mfma_f32_16x16x32_bf16(qf[kk], kb[ni], sacc[ni], 0, 0, 0);
        }
        float mload[8];
#pragma unroll
        for (int ni = 0; ni < 8; ni++) mload[ni] = mk[ni * 16 + c16];

        // online softmax (P left in sacc)
#pragma unroll
        for (int r = 0; r < 4; r++) {
            float sv[8];
            float rm = -3e38f;
#pragma unroll
            for (int ni = 0; ni < 8; ni++) {
                sv[ni] = sacc[ni][r] * scale + mload[ni];
                rm = fmaxf(rm, sv[ni]);
            }
#pragma unroll
            for (int mm = 1; mm < 16; mm <<= 1) rm = fmaxf(rm, __shfl_xor(rm, mm, 64));
            float mnew = fmaxf(mst[r], rm);
            float alpha = __expf(mst[r] - mnew);
            float rs = 0.f;
#pragma unroll
            for (int ni = 0; ni < 8; ni++) {
                float p = __expf(sv[ni] - mnew);
                rs += p;
                sacc[ni][r] = p;
            }
#pragma unroll
            for (int mm = 1; mm < 16; mm <<= 1) rs += __shfl_xor(rs, mm, 64);
            lst[r] = lst[r] * alpha + rs;
            mst[r] = mnew;
#pragma unroll
            for (int nei = 0; nei < 4; nei++) of[nei][r] *= alpha;
        }
        __syncthreads();   // all waves done reading K before P overwrites region

        // write P (bf16) into KP as [64 q][128 s], swizzled
#pragma unroll
        for (int ni = 0; ni < 8; ni++)
#pragma unroll
            for (int r = 0; r < 4; r++) {
                int row = w * 16 + quad * 4 + r;
                int col = ni * 16 + c16;
                int p = (col >> 3) ^ (row & 15);
                KP[row * 128 + p * 8 + (col & 7)] = f2bf(sacc[ni][r]);
            }

        // O += P @ V (own wave's P rows only; no barrier needed before reads)
#pragma unroll
        for (int kk = 0; kk < 4; kk++) {
            bf16x8 pa, vb[4];
            {
                int row = w * 16 + c16;
                int p = (kk * 4 + quad) ^ c16;
                pa = *(const bf16x8*)(KP + row * 128 + p * 8);
            }
#pragma unroll
            for (int nei = 0; nei < 4; nei++) {
                int e = nei * 16 + c16;
                int p = (kk * 4 + quad) ^ c16;
                vb[nei] = *(const bf16x8*)(Vt + e * 128 + p * 8);
            }
#pragma unroll
            for (int nei = 0; nei < 4; nei++)
                of[nei] = __builtin_amdgcn_mfma_f32_16x16x32_bf16(pa, vb[nei], of[nei], 0, 0, 0);
        }
        __syncthreads();   // P/Vt reads done before next chunk staging
    }

    // write partials
    int base = ((sp * NHEAD + h) * 32 + blockIdx.x);
#pragma unroll
    for (int nei = 0; nei < 4; nei++)
#pragma unroll
        for (int r = 0; r < 4; r++) {
            int rin = w * 16 + quad * 4 + r;
            Opart[(size_t)base * 4096 + rin * 64 + nei * 16 + c16] = of[nei][r];
        }
    if (c16 == 0) {
#pragma unroll
        for (int r = 0; r < 4; r++) {
            int rin = w * 16 + quad * 4 + r;
            Mpart[(size_t)base * 64 + rin] = mst[r];
            Lpart[(size_t)base * 64 + rin] = lst[r];
        }
    }
}

// ---------------- combine partials + mean-pool over TQ ----------------
// wave per (pooled row, head); lane = e. grid 768 x 256.
__global__ __launch_bounds__(256) void combine_kernel(
    const float* __restrict__ Opart, const float* __restrict__ Mpart, const float* __restrict__ Lpart,
    float* __restrict__ pooled)
{
    int gi = blockIdx.x * 4 + (threadIdx.x >> 6);   // 0..3071
    int e = threadIdx.x & 63;
    int lq = gi / NHEAD, h = gi - lq * NHEAD;
    float acc = 0.f;
#pragma unroll
    for (int row = 0; row < 8; row++) {
        int qrow = lq * 8 + row;
        int qt = qrow >> 6, rin = qrow & 63;
        float m[NSPLIT], lv[NSPLIT];
        float M = -3e38f;
#pragma unroll
        for (int sp = 0; sp < NSPLIT; sp++) {
            int base = (sp * NHEAD + h) * 32 + qt;
            m[sp] = Mpart[(size_t)base * 64 + rin];
            lv[sp] = Lpart[(size_t)base * 64 + rin];
            M = fmaxf(M, m[sp]);
        }
        float Ls = 0.f, val = 0.f;
#pragma unroll
        for (int sp = 0; sp < NSPLIT; sp++) {
            int base = (sp * NHEAD + h) * 32 + qt;
            float wgt = __expf(m[sp] - M);
            Ls += lv[sp] * wgt;
            val += wgt * Opart[(size_t)base * 4096 + rin * 64 + e];
        }
        acc += val / Ls;
    }
    pooled[(size_t)lq * DDIM + h * EDIM + e] = acc * 0.125f;
}

// ---------------- init d_out with bias ----------------
__global__ __launch_bounds__(256) void bias_init_kernel(const float* __restrict__ bo, float* __restrict__ y)
{
    int f = blockIdx.x * 256 + threadIdx.x;   // 49152 float4s
    int c4 = f % 192;
    ((f32x4*)y)[f] = ((const f32x4*)bo)[c4];
}

// ---------------- final fp32 GEMM y += pooled(256,768) @ Wo(768,768)^T, split-K + atomics ----------------
__global__ __launch_bounds__(256) void wo_kernel(
    const float* __restrict__ pooled, const float* __restrict__ Wo, float* __restrict__ y)
{
    __shared__ float As[64 * 65];
    int m0 = blockIdx.x * 64, n0 = blockIdx.y * 128, k0 = blockIdx.z * 64;
    int t = threadIdx.x;
#pragma unroll
    for (int i = 0; i < 16; i++) {
        int f = i * 256 + t;
        int r = f >> 6, c = f & 63;
        As[r * 65 + c] = pooled[(size_t)(m0 + r) * DDIM + k0 + c];
    }
    __syncthreads();
    int tx = t & 31, my = t >> 5;
    float acc[8][4];
#pragma unroll
    for (int r = 0; r < 8; r++)
#pragma unroll
        for (int j = 0; j < 4; j++) acc[r][j] = 0.f;
    for (int kq = 0; kq < 16; kq++) {
        f32x4 bj[4];
#pragma unroll
        for (int j = 0; j < 4; j++)
            bj[j] = *(const f32x4*)(Wo + (size_t)(n0 + tx * 4 + j) * DDIM + k0 + kq * 4);
#pragma unroll
        for (int jj = 0; jj < 4; jj++) {
            int k = kq * 4 + jj;
            float a8[8];
#pragma unroll
            for (int r = 0; r < 8; r++) a8[r] = As[(my * 8 + r) * 65 + k];
#pragma unroll
            for (int r = 0; r < 8; r++)
#pragma unroll
                for (int j = 0; j < 4; j++) acc[r][j] += a8[r] * bj[j][jj];
        }
    }
#pragma unroll
    for (int r = 0; r < 8; r++)
#pragma unroll
        for (int j = 0; j < 4; j++)
            atomicAdd(&y[(size_t)(m0 + my * 8 + r) * DDIM + n0 + tx * 4 + j], acc[r][j]);
}

extern "C" void kernel_launch(void* const* d_in, const int* in_sizes, int n_in,
                              void* d_out, int out_size, void* d_ws, size_t ws_size,
                              hipStream_t stream)
{
    const float* tgt     = (const float*)d_in[0];
    const float* keyb    = (const float*)d_in[1];
    const float* valb    = (const float*)d_in[2];
    const int*   mask    = (const int*)d_in[3];
    const float* Wq      = (const float*)d_in[4];
    const float* bq      = (const float*)d_in[5];
    const float* Wk      = (const float*)d_in[6];
    const float* bk      = (const float*)d_in[7];
    const float* Wv      = (const float*)d_in[8];
    const float* bv      = (const float*)d_in[9];
    const float* Wo      = (const float*)d_in[10];
    const float* bo      = (const float*)d_in[11];
    const float* g_q     = (const float*)d_in[12];
    const float* beta_q  = (const float*)d_in[13];
    const float* g_kv    = (const float*)d_in[14];
    const float* beta_kv = (const float*)d_in[15];
    float* y = (float*)d_out;

    char* ws = (char*)d_ws;
    // persistent across phases:
    u16* Qm  = (u16*)(ws + 0);          // 3,145,728
    u16* Km  = (u16*)(ws + 3145728);    // 3,145,728
    u16* VmT = (u16*)(ws + 6291456);    // 3,145,728
    // phase A (dead after proj_kernel):
    u16* lnQ = (u16*)(ws + 9437184);
    u16* lnK = (u16*)(ws + 12582912);
    u16* lnV = (u16*)(ws + 15728640);
    u16* Wqb = (u16*)(ws + 18874368);
    u16* Wkb = (u16*)(ws + 20054016);
    u16* Wvb = (u16*)(ws + 21233664);
    // phase B (aliases phase A region; written by attn_kernel onward):
    float* Opart  = (float*)(ws + 9437184);   // 25,165,824
    float* Mpart  = (float*)(ws + 34603008);  // 393,216
    float* Lpart  = (float*)(ws + 34996224);  // 393,216
    float* pooled = (float*)(ws + 35389440);  // 786,432

    hipLaunchKernelGGL(castw_kernel, dim3(1728), dim3(256), 0, stream,
                       Wq, Wk, Wv, Wqb, Wkb, Wvb);
    hipLaunchKernelGGL(ln_kernel, dim3(1536), dim3(256), 0, stream,
                       tgt, keyb, valb, g_q, beta_q, g_kv, beta_kv, lnQ, lnK, lnV);
    hipLaunchKernelGGL(proj_kernel, dim3(6, 16, 3), dim3(256), 0, stream,
                       lnQ, lnK, lnV, Wqb, Wkb, Wvb, bq, bk, bv, Qm, Km, VmT);
    hipLaunchKernelGGL(attn_kernel, dim3(32, 12, 4), dim3(256), 0, stream,
                       Qm, Km, VmT, mask, Opart, Mpart, Lpart);
    hipLaunchKernelGGL(combine_kernel, dim3(768), dim3(256), 0, stream,
                       Opart, Mpart, Lpart, pooled);
    hipLaunchKernelGGL(bias_init_kernel, dim3(192), dim3(256), 0, stream, bo, y);
    hipLaunchKernelGGL(wo_kernel, dim3(4, 6, 12), dim3(256), 0, stream,
                       pooled, Wo, y);
}

// Round 3
// 209.664 us; speedup vs baseline: 1.2178x; 1.2051x over previous
//
#include <hip/hip_runtime.h>
#include <stdint.h>

typedef unsigned short u16;
typedef float f32x4 __attribute__((ext_vector_type(4)));
typedef __bf16 bf16x8 __attribute__((ext_vector_type(8)));

#define DDIM 768
#define NHEAD 12
#define EDIM 64
#define SREAL 2000
#define SPAD 2048
#define NQ 2048
#define NSPLIT 4

__device__ __forceinline__ u16 f2bf(float f) {
    unsigned u = __float_as_uint(f);
    return (u16)((u + 0x7fffu + ((u >> 16) & 1u)) >> 16);
}

__device__ __forceinline__ void async16(const void* g, void* l) {
    __builtin_amdgcn_global_load_lds(
        (const __attribute__((address_space(1))) void*)(const void*)g,
        (__attribute__((address_space(3))) void*)l, 16, 0, 0);
}

// ---------------- fused: cast weights -> bf16 (Wq pre-scaled by 0.125) + layernorm ----------------
__global__ __launch_bounds__(256) void prep_kernel(
    const float* __restrict__ Wq, const float* __restrict__ Wk, const float* __restrict__ Wv,
    u16* __restrict__ Wqb, u16* __restrict__ Wkb, u16* __restrict__ Wvb,
    const float* __restrict__ tgt, const float* __restrict__ keyb, const float* __restrict__ valb,
    const float* __restrict__ g_q, const float* __restrict__ b_q,
    const float* __restrict__ g_kv, const float* __restrict__ b_kv,
    u16* __restrict__ lnQ, u16* __restrict__ lnK, u16* __restrict__ lnV)
{
    int bx = blockIdx.x;
    if (bx < 1728) {
        int g = bx * 256 + threadIdx.x;   // float4 index, total 3*147456
        const float* src; u16* dst; int idx; float sc;
        if (g < 147456)      { src = Wq; dst = Wqb; idx = g; sc = 0.125f; }
        else if (g < 294912) { src = Wk; dst = Wkb; idx = g - 147456; sc = 1.f; }
        else                 { src = Wv; dst = Wvb; idx = g - 294912; sc = 1.f; }
        f32x4 a = ((const f32x4*)src)[idx];
        ushort4 o;
        o.x = f2bf(a[0] * sc); o.y = f2bf(a[1] * sc);
        o.z = f2bf(a[2] * sc); o.w = f2bf(a[3] * sc);
        ((ushort4*)dst)[idx] = o;
        return;
    }
    int row = (bx - 1728) * 4 + (threadIdx.x >> 6);   // 0..6143
    int l = threadIdx.x & 63;
    const float* src = nullptr; const float* gg; const float* bb; u16* dst;
    bool zero = false;
    if (row < 2048) {
        src = tgt + (size_t)row * DDIM; gg = g_q; bb = b_q; dst = lnQ + (size_t)row * DDIM;
    } else if (row < 4096) {
        int r = row - 2048; gg = g_kv; bb = b_kv; dst = lnK + (size_t)r * DDIM;
        if (r < SREAL) src = keyb + (size_t)r * DDIM; else zero = true;
    } else {
        int r = row - 4096; gg = g_kv; bb = b_kv; dst = lnV + (size_t)r * DDIM;
        if (r < SREAL) src = valb + (size_t)r * DDIM; else zero = true;
    }
    if (zero) {
        ushort4 z; z.x = 0; z.y = 0; z.z = 0; z.w = 0;
#pragma unroll
        for (int i = 0; i < 3; i++) ((ushort4*)dst)[l + 64 * i] = z;
        return;
    }
    f32x4 a[3];
#pragma unroll
    for (int i = 0; i < 3; i++) a[i] = ((const f32x4*)src)[l + 64 * i];
    float s = 0.f;
#pragma unroll
    for (int i = 0; i < 3; i++) { s += a[i][0] + a[i][1] + a[i][2] + a[i][3]; }
#pragma unroll
    for (int m = 1; m < 64; m <<= 1) s += __shfl_xor(s, m, 64);
    float mean = s * (1.f / 768.f);
    float v = 0.f;
#pragma unroll
    for (int i = 0; i < 3; i++)
#pragma unroll
        for (int j = 0; j < 4; j++) { float d = a[i][j] - mean; v += d * d; }
#pragma unroll
    for (int m = 1; m < 64; m <<= 1) v += __shfl_xor(v, m, 64);
    float rstd = rsqrtf(v * (1.f / 768.f) + 1e-5f);
#pragma unroll
    for (int i = 0; i < 3; i++) {
        f32x4 g4 = ((const f32x4*)gg)[l + 64 * i];
        f32x4 b4 = ((const f32x4*)bb)[l + 64 * i];
        ushort4 o;
        o.x = f2bf((a[i][0] - mean) * rstd * g4[0] + b4[0]);
        o.y = f2bf((a[i][1] - mean) * rstd * g4[1] + b4[1]);
        o.z = f2bf((a[i][2] - mean) * rstd * g4[2] + b4[2]);
        o.w = f2bf((a[i][3] - mean) * rstd * g4[3] + b4[3]);
        ((ushort4*)dst)[l + 64 * i] = o;
    }
}

// ---------------- batched projection GEMM: C = A(M,768) @ W(768,768)^T + bias ----------------
// 128x128 tile, BK=64, double-buffered LDS (loads for kt+1 issued before compute of kt).
__global__ __launch_bounds__(256) void proj_kernel(
    const u16* __restrict__ lnQ, const u16* __restrict__ lnK, const u16* __restrict__ lnV,
    const u16* __restrict__ Wqb, const u16* __restrict__ Wkb, const u16* __restrict__ Wvb,
    const float* __restrict__ bq, const float* __restrict__ bk, const float* __restrict__ bv,
    u16* __restrict__ Qm, u16* __restrict__ Km, u16* __restrict__ VmT)
{
    __shared__ u16 Ash[2][128 * 64];
    __shared__ u16 Bsh[2][128 * 64];
    const u16* A; const u16* W; const float* bias; float bscale; int z = blockIdx.z;
    if (z == 0)      { A = lnQ; W = Wqb; bias = bq; bscale = 0.125f; }
    else if (z == 1) { A = lnK; W = Wkb; bias = bk; bscale = 1.f; }
    else             { A = lnV; W = Wvb; bias = bv; bscale = 1.f; }
    int n0 = blockIdx.x * 128, m0 = blockIdx.y * 128;
    int t = threadIdx.x, l = t & 63, quad = l >> 4, c16 = l & 15;
    int wv = t >> 6, wm = wv >> 1, wn = wv & 1;

    f32x4 acc[4][4];
    f32x4 zz = {0.f, 0.f, 0.f, 0.f};
#pragma unroll
    for (int mi = 0; mi < 4; mi++)
#pragma unroll
        for (int ni = 0; ni < 4; ni++) acc[mi][ni] = zz;

    // prologue: stage tile 0 into buffer 0
#pragma unroll
    for (int i = 0; i < 4; i++) {
        int ch = i * 256 + t;
        int r = ch >> 3, pc = ch & 7, jc = pc ^ (r & 7);
        async16(A + (size_t)(m0 + r) * DDIM + jc * 8, (char*)Ash[0] + ch * 16);
        async16(W + (size_t)(n0 + r) * DDIM + jc * 8, (char*)Bsh[0] + ch * 16);
    }
    for (int kt = 0; kt < 12; kt++) {
        int cur = kt & 1;
        __syncthreads();   // drains loads for tile kt
        if (kt < 11) {
            int k0 = (kt + 1) * 64;
#pragma unroll
            for (int i = 0; i < 4; i++) {
                int ch = i * 256 + t;
                int r = ch >> 3, pc = ch & 7, jc = pc ^ (r & 7);
                async16(A + (size_t)(m0 + r) * DDIM + k0 + jc * 8, (char*)Ash[cur ^ 1] + ch * 16);
                async16(W + (size_t)(n0 + r) * DDIM + k0 + jc * 8, (char*)Bsh[cur ^ 1] + ch * 16);
            }
        }
#pragma unroll
        for (int kk = 0; kk < 2; kk++) {
            bf16x8 a[4], b[4];
#pragma unroll
            for (int mi = 0; mi < 4; mi++) {
                int row = wm * 64 + mi * 16 + c16;
                int p = (kk * 4 + quad) ^ (row & 7);
                a[mi] = *(const bf16x8*)(Ash[cur] + row * 64 + p * 8);
            }
#pragma unroll
            for (int ni = 0; ni < 4; ni++) {
                int row = wn * 64 + ni * 16 + c16;
                int p = (kk * 4 + quad) ^ (row & 7);
                b[ni] = *(const bf16x8*)(Bsh[cur] + row * 64 + p * 8);
            }
#pragma unroll
            for (int mi = 0; mi < 4; mi++)
#pragma unroll
                for (int ni = 0; ni < 4; ni++)
                    acc[mi][ni] = __builtin_amdgcn_mfma_f32_16x16x32_bf16(a[mi], b[ni], acc[mi][ni], 0, 0, 0);
        }
        __syncthreads();   // all waves done with buffer cur before it is restaged
    }
    if (z < 2) {
        u16* out = (z == 0) ? Qm : Km;
        int Mact = (z == 0) ? NQ : SREAL;
#pragma unroll
        for (int mi = 0; mi < 4; mi++)
#pragma unroll
            for (int ni = 0; ni < 4; ni++) {
                int n = n0 + wn * 64 + ni * 16 + c16;
                float bval = bias[n] * bscale;
#pragma unroll
                for (int r = 0; r < 4; r++) {
                    int m = m0 + wm * 64 + mi * 16 + quad * 4 + r;
                    float val = (m < Mact) ? (acc[mi][ni][r] + bval) : 0.f;
                    out[(size_t)m * DDIM + n] = f2bf(val);
                }
            }
    } else {
        // V: write transposed [n (768)][m (2048)], zero pad rows m>=2000
#pragma unroll
        for (int mi = 0; mi < 4; mi++)
#pragma unroll
            for (int ni = 0; ni < 4; ni++) {
                int n = n0 + wn * 64 + ni * 16 + c16;
                float bval = bias[n];
                int mbase = m0 + wm * 64 + mi * 16 + quad * 4;
                ushort4 o;
                o.x = (mbase + 0 < SREAL) ? f2bf(acc[mi][ni][0] + bval) : (u16)0;
                o.y = (mbase + 1 < SREAL) ? f2bf(acc[mi][ni][1] + bval) : (u16)0;
                o.z = (mbase + 2 < SREAL) ? f2bf(acc[mi][ni][2] + bval) : (u16)0;
                o.w = (mbase + 3 < SREAL) ? f2bf(acc[mi][ni][3] + bval) : (u16)0;
                *(ushort4*)(VmT + (size_t)n * SPAD + mbase) = o;
            }
    }
}

// ---------------- split-S flash attention, no-max softmax ----------------
// 1536 blocks 1-D, XCD-swizzled: b&7 = XCD slot, 6 (sp,h) groups per XCD.
__global__ __launch_bounds__(256, 4) void attn_kernel(
    const u16* __restrict__ Qm, const u16* __restrict__ Km, const u16* __restrict__ VmT,
    const int* __restrict__ bank_mask,
    float* __restrict__ Opart, float* __restrict__ Lpart)
{
    __shared__ u16 KP[128 * 64];   // K chunk [128 s][64 e] -> reused as P [64 q][128 s]
    __shared__ u16 Vt[64 * 128];   // [e][s], XOR-swizzled
    __shared__ float mk[128];      // multiplicative mask 0/1
    int b = blockIdx.x;
    int xcd = b & 7, j = b >> 3;          // j in [0,192)
    int grp = xcd * 6 + (j >> 5);         // 48 groups: grp = sp*NHEAD + h
    int q = j & 31;
    int sp = grp / NHEAD, h = grp - sp * NHEAD;
    int q0 = q * 64;
    int t = threadIdx.x, w = t >> 6, l = t & 63, quad = l >> 4, c16 = l & 15;

    bf16x8 qf[2];
#pragma unroll
    for (int kk = 0; kk < 2; kk++) {
        int row = q0 + w * 16 + c16;
        qf[kk] = *(const bf16x8*)(Qm + (size_t)row * DDIM + h * EDIM + kk * 32 + quad * 8);
    }
    bf16x8 ones;
#pragma unroll
    for (int i = 0; i < 8; i++) ones[i] = (__bf16)1.0f;

    f32x4 zz = {0.f, 0.f, 0.f, 0.f};
    f32x4 of[4], ol;
#pragma unroll
    for (int nei = 0; nei < 4; nei++) of[nei] = zz;
    ol = zz;

    for (int sc = 0; sc < 4; sc++) {
        int s0 = sp * 512 + sc * 128;
        // stage K chunk [128][64] swizzled
#pragma unroll
        for (int i = 0; i < 4; i++) {
            int ch = i * 256 + t;
            int r = ch >> 3, pc = ch & 7, jc = pc ^ (r & 7);
            async16(Km + (size_t)(s0 + r) * DDIM + h * EDIM + jc * 8, (char*)KP + ch * 16);
        }
        // stage V^T chunk [64 e][128 s] swizzled
#pragma unroll
        for (int i = 0; i < 4; i++) {
            int ch = i * 256 + t;
            int e = ch >> 4, pc = ch & 15, jc = pc ^ (e & 15);
            async16(VmT + (size_t)(h * EDIM + e) * SPAD + s0 + jc * 8, (char*)Vt + ch * 16);
        }
        if (t < 128) {
            int s = s0 + t;
            mk[t] = (s < SREAL && bank_mask[s] != 0) ? 1.f : 0.f;
        }
        __syncthreads();

        // QK^T (scale pre-folded into Wq): wave's 16 q-rows x 128 s-cols
        f32x4 sacc[8];
#pragma unroll
        for (int ni = 0; ni < 8; ni++) sacc[ni] = zz;
#pragma unroll
        for (int kk = 0; kk < 2; kk++) {
            bf16x8 kb[8];
#pragma unroll
            for (int ni = 0; ni < 8; ni++) {
                int row = ni * 16 + c16;
                int p = (kk * 4 + quad) ^ (row & 7);
                kb[ni] = *(const bf16x8*)(KP + row * 64 + p * 8);
            }
#pragma unroll
            for (int ni = 0; ni < 8; ni++)
                sacc[ni] = __builtin_amdgcn_mfma_f32_16x16x32_bf16(qf[kk], kb[ni], sacc[ni], 0, 0, 0);
        }
        // p = exp(s) * mask  (no max subtraction; scores are O(1))
        float m01[8];
#pragma unroll
        for (int ni = 0; ni < 8; ni++) m01[ni] = mk[ni * 16 + c16];
#pragma unroll
        for (int ni = 0; ni < 8; ni++)
#pragma unroll
            for (int r = 0; r < 4; r++)
                sacc[ni][r] = __expf(sacc[ni][r]) * m01[ni];
        __syncthreads();   // all waves done reading K before P overwrites region

        // write P (bf16) into KP as [64 q][128 s], swizzled
#pragma unroll
        for (int ni = 0; ni < 8; ni++)
#pragma unroll
            for (int r = 0; r < 4; r++) {
                int row = w * 16 + quad * 4 + r;
                int col = ni * 16 + c16;
                int p = (col >> 3) ^ (row & 15);
                KP[row * 128 + p * 8 + (col & 7)] = f2bf(sacc[ni][r]);
            }

        // O += P @ V, l += P @ 1 (own wave's P rows only)
#pragma unroll
        for (int kk = 0; kk < 4; kk++) {
            bf16x8 pa, vb[4];
            {
                int row = w * 16 + c16;
                int p = (kk * 4 + quad) ^ c16;
                pa = *(const bf16x8*)(KP + row * 128 + p * 8);
            }
#pragma unroll
            for (int nei = 0; nei < 4; nei++) {
                int e = nei * 16 + c16;
                int p = (kk * 4 + quad) ^ c16;
                vb[nei] = *(const bf16x8*)(Vt + e * 128 + p * 8);
            }
#pragma unroll
            for (int nei = 0; nei < 4; nei++)
                of[nei] = __builtin_amdgcn_mfma_f32_16x16x32_bf16(pa, vb[nei], of[nei], 0, 0, 0);
            ol = __builtin_amdgcn_mfma_f32_16x16x32_bf16(pa, ones, ol, 0, 0, 0);
        }
        __syncthreads();   // P/Vt reads done before next chunk staging
    }

    // write partials (unnormalized O and row-sum l; additive across splits)
    int base = (sp * NHEAD + h) * 32 + q;
#pragma unroll
    for (int nei = 0; nei < 4; nei++)
#pragma unroll
        for (int r = 0; r < 4; r++) {
            int rin = w * 16 + quad * 4 + r;
            Opart[(size_t)base * 4096 + rin * 64 + nei * 16 + c16] = of[nei][r];
        }
    if (c16 == 0) {
#pragma unroll
        for (int r = 0; r < 4; r++) {
            int rin = w * 16 + quad * 4 + r;
            Lpart[(size_t)base * 64 + rin] = ol[r];
        }
    }
}

// ---------------- combine partials + mean-pool over TQ; also init y with bias ----------------
__global__ __launch_bounds__(256) void combine_kernel(
    const float* __restrict__ Opart, const float* __restrict__ Lpart,
    const float* __restrict__ bo, float* __restrict__ pooled, float* __restrict__ y)
{
    // y bias init: 49152 float4s over 196608 threads
    int tid = blockIdx.x * 256 + threadIdx.x;
    if (tid < 49152) {
        int c4 = tid % 192;
        ((f32x4*)y)[tid] = ((const f32x4*)bo)[c4];
    }
    int gi = blockIdx.x * 4 + (threadIdx.x >> 6);   // 0..3071
    int e = threadIdx.x & 63;
    int lq = gi / NHEAD, h = gi - lq * NHEAD;
    float acc = 0.f;
#pragma unroll
    for (int row = 0; row < 8; row++) {
        int qrow = lq * 8 + row;
        int qt = qrow >> 6, rin = qrow & 63;
        float Ls = 0.f, val = 0.f;
#pragma unroll
        for (int sp = 0; sp < NSPLIT; sp++) {
            int base = (sp * NHEAD + h) * 32 + qt;
            Ls += Lpart[(size_t)base * 64 + rin];
            val += Opart[(size_t)base * 4096 + rin * 64 + e];
        }
        acc += val / Ls;
    }
    pooled[(size_t)lq * DDIM + h * EDIM + e] = acc * 0.125f;
}

// ---------------- final fp32 GEMM y += pooled(256,768) @ Wo(768,768)^T, split-K=6 + atomics ----------------
__global__ __launch_bounds__(256) void wo_kernel(
    const float* __restrict__ pooled, const float* __restrict__ Wo, float* __restrict__ y)
{
    __shared__ float As[32 * 132];
    int m0 = blockIdx.x * 32, n0 = blockIdx.y * 128, k0 = blockIdx.z * 128;
    int t = threadIdx.x;
#pragma unroll
    for (int i = 0; i < 4; i++) {
        int f = i * 256 + t;        // 1024 float4s = 32 rows x 32 f4
        int r = f >> 5, c4 = f & 31;
        f32x4 v = *(const f32x4*)(pooled + (size_t)(m0 + r) * DDIM + k0 + c4 * 4);
        *(f32x4*)(As + r * 132 + c4 * 4) = v;
    }
    __syncthreads();
    int tx = t & 31, my = t >> 5;   // tx: 4 n-cols, my: 4 m-rows
    float acc[4][4];
#pragma unroll
    for (int r = 0; r < 4; r++)
#pragma unroll
        for (int j = 0; j < 4; j++) acc[r][j] = 0.f;
    for (int kq = 0; kq < 32; kq++) {
        f32x4 bj[4];
#pragma unroll
        for (int j = 0; j < 4; j++)
            bj[j] = *(const f32x4*)(Wo + (size_t)(n0 + tx * 4 + j) * DDIM + k0 + kq * 4);
        f32x4 a4[4];
#pragma unroll
        for (int r = 0; r < 4; r++)
            a4[r] = *(const f32x4*)(As + (my * 4 + r) * 132 + kq * 4);
#pragma unroll
        for (int jj = 0; jj < 4; jj++)
#pragma unroll
            for (int r = 0; r < 4; r++)
#pragma unroll
                for (int j = 0; j < 4; j++) acc[r][j] += a4[r][jj] * bj[j][jj];
    }
#pragma unroll
    for (int r = 0; r < 4; r++)
#pragma unroll
        for (int j = 0; j < 4; j++)
            atomicAdd(&y[(size_t)(m0 + my * 4 + r) * DDIM + n0 + tx * 4 + j], acc[r][j]);
}

extern "C" void kernel_launch(void* const* d_in, const int* in_sizes, int n_in,
                              void* d_out, int out_size, void* d_ws, size_t ws_size,
                              hipStream_t stream)
{
    const float* tgt     = (const float*)d_in[0];
    const float* keyb    = (const float*)d_in[1];
    const float* valb    = (const float*)d_in[2];
    const int*   mask    = (const int*)d_in[3];
    const float* Wq      = (const float*)d_in[4];
    const float* bq      = (const float*)d_in[5];
    const float* Wk      = (const float*)d_in[6];
    const float* bk      = (const float*)d_in[7];
    const float* Wv      = (const float*)d_in[8];
    const float* bv      = (const float*)d_in[9];
    const float* Wo      = (const float*)d_in[10];
    const float* bo      = (const float*)d_in[11];
    const float* g_q     = (const float*)d_in[12];
    const float* beta_q  = (const float*)d_in[13];
    const float* g_kv    = (const float*)d_in[14];
    const float* beta_kv = (const float*)d_in[15];
    float* y = (float*)d_out;

    char* ws = (char*)d_ws;
    // persistent across phases:
    u16* Qm  = (u16*)(ws + 0);          // 3,145,728
    u16* Km  = (u16*)(ws + 3145728);    // 3,145,728
    u16* VmT = (u16*)(ws + 6291456);    // 3,145,728
    // phase A (dead after proj_kernel):
    u16* lnQ = (u16*)(ws + 9437184);
    u16* lnK = (u16*)(ws + 12582912);
    u16* lnV = (u16*)(ws + 15728640);
    u16* Wqb = (u16*)(ws + 18874368);
    u16* Wkb = (u16*)(ws + 20054016);
    u16* Wvb = (u16*)(ws + 21233664);
    // phase B (aliases phase A region):
    float* Opart  = (float*)(ws + 9437184);   // 25,165,824
    float* Lpart  = (float*)(ws + 34603008);  // 393,216
    float* pooled = (float*)(ws + 34996224);  // 786,432

    hipLaunchKernelGGL(prep_kernel, dim3(3264), dim3(256), 0, stream,
                       Wq, Wk, Wv, Wqb, Wkb, Wvb,
                       tgt, keyb, valb, g_q, beta_q, g_kv, beta_kv, lnQ, lnK, lnV);
    hipLaunchKernelGGL(proj_kernel, dim3(6, 16, 3), dim3(256), 0, stream,
                       lnQ, lnK, lnV, Wqb, Wkb, Wvb, bq, bk, bv, Qm, Km, VmT);
    hipLaunchKernelGGL(attn_kernel, dim3(1536), dim3(256), 0, stream,
                       Qm, Km, VmT, mask, Opart, Lpart);
    hipLaunchKernelGGL(combine_kernel, dim3(768), dim3(256), 0, stream,
                       Opart, Lpart, bo, pooled, y);
    hipLaunchKernelGGL(wo_kernel, dim3(8, 6, 6), dim3(256), 0, stream,
                       pooled, Wo, y);
}

// Round 4
// 201.487 us; speedup vs baseline: 1.2673x; 1.0406x over previous
//
#include <hip/hip_runtime.h>
#include <stdint.h>

typedef unsigned short u16;
typedef float f32x4 __attribute__((ext_vector_type(4)));
typedef __bf16 bf16x8 __attribute__((ext_vector_type(8)));

#define DDIM 768
#define NHEAD 12
#define EDIM 64
#define SREAL 2000
#define SPAD 2048
#define NQ 2048
#define NSPLIT 4

__device__ __forceinline__ u16 f2bf(float f) {
    unsigned u = __float_as_uint(f);
    return (u16)((u + 0x7fffu + ((u >> 16) & 1u)) >> 16);
}
__device__ __forceinline__ float bf2f(u16 v) {
    return __uint_as_float(((unsigned)v) << 16);
}

__device__ __forceinline__ void async16(const void* g, void* l) {
    __builtin_amdgcn_global_load_lds(
        (const __attribute__((address_space(1))) void*)(const void*)g,
        (__attribute__((address_space(3))) void*)l, 16, 0, 0);
}

// ---------------- fused: cast weights -> bf16 (Wq pre-scaled by 0.125) + layernorm ----------------
__global__ __launch_bounds__(256) void prep_kernel(
    const float* __restrict__ Wq, const float* __restrict__ Wk, const float* __restrict__ Wv,
    u16* __restrict__ Wqb, u16* __restrict__ Wkb, u16* __restrict__ Wvb,
    const float* __restrict__ tgt, const float* __restrict__ keyb, const float* __restrict__ valb,
    const float* __restrict__ g_q, const float* __restrict__ b_q,
    const float* __restrict__ g_kv, const float* __restrict__ b_kv,
    u16* __restrict__ lnQ, u16* __restrict__ lnK, u16* __restrict__ lnV)
{
    int bx = blockIdx.x;
    if (bx < 1728) {
        int g = bx * 256 + threadIdx.x;
        const float* src; u16* dst; int idx; float sc;
        if (g < 147456)      { src = Wq; dst = Wqb; idx = g; sc = 0.125f; }
        else if (g < 294912) { src = Wk; dst = Wkb; idx = g - 147456; sc = 1.f; }
        else                 { src = Wv; dst = Wvb; idx = g - 294912; sc = 1.f; }
        f32x4 a = ((const f32x4*)src)[idx];
        ushort4 o;
        o.x = f2bf(a[0] * sc); o.y = f2bf(a[1] * sc);
        o.z = f2bf(a[2] * sc); o.w = f2bf(a[3] * sc);
        ((ushort4*)dst)[idx] = o;
        return;
    }
    int row = (bx - 1728) * 4 + (threadIdx.x >> 6);
    int l = threadIdx.x & 63;
    const float* src = nullptr; const float* gg; const float* bb; u16* dst;
    bool zero = false;
    if (row < 2048) {
        src = tgt + (size_t)row * DDIM; gg = g_q; bb = b_q; dst = lnQ + (size_t)row * DDIM;
    } else if (row < 4096) {
        int r = row - 2048; gg = g_kv; bb = b_kv; dst = lnK + (size_t)r * DDIM;
        if (r < SREAL) src = keyb + (size_t)r * DDIM; else zero = true;
    } else {
        int r = row - 4096; gg = g_kv; bb = b_kv; dst = lnV + (size_t)r * DDIM;
        if (r < SREAL) src = valb + (size_t)r * DDIM; else zero = true;
    }
    if (zero) {
        ushort4 z; z.x = 0; z.y = 0; z.z = 0; z.w = 0;
#pragma unroll
        for (int i = 0; i < 3; i++) ((ushort4*)dst)[l + 64 * i] = z;
        return;
    }
    f32x4 a[3];
#pragma unroll
    for (int i = 0; i < 3; i++) a[i] = ((const f32x4*)src)[l + 64 * i];
    float s = 0.f;
#pragma unroll
    for (int i = 0; i < 3; i++) { s += a[i][0] + a[i][1] + a[i][2] + a[i][3]; }
#pragma unroll
    for (int m = 1; m < 64; m <<= 1) s += __shfl_xor(s, m, 64);
    float mean = s * (1.f / 768.f);
    float v = 0.f;
#pragma unroll
    for (int i = 0; i < 3; i++)
#pragma unroll
        for (int j = 0; j < 4; j++) { float d = a[i][j] - mean; v += d * d; }
#pragma unroll
    for (int m = 1; m < 64; m <<= 1) v += __shfl_xor(v, m, 64);
    float rstd = rsqrtf(v * (1.f / 768.f) + 1e-5f);
#pragma unroll
    for (int i = 0; i < 3; i++) {
        f32x4 g4 = ((const f32x4*)gg)[l + 64 * i];
        f32x4 b4 = ((const f32x4*)bb)[l + 64 * i];
        ushort4 o;
        o.x = f2bf((a[i][0] - mean) * rstd * g4[0] + b4[0]);
        o.y = f2bf((a[i][1] - mean) * rstd * g4[1] + b4[1]);
        o.z = f2bf((a[i][2] - mean) * rstd * g4[2] + b4[2]);
        o.w = f2bf((a[i][3] - mean) * rstd * g4[3] + b4[3]);
        ((ushort4*)dst)[l + 64 * i] = o;
    }
}

// ---------------- batched projection GEMM: C = A(M,768) @ W(768,768)^T + bias ----------------
// 128m x 64n tile, BK=64 double-buffered, 576 blocks (2.25/CU).
__global__ __launch_bounds__(256) void proj_kernel(
    const u16* __restrict__ lnQ, const u16* __restrict__ lnK, const u16* __restrict__ lnV,
    const u16* __restrict__ Wqb, const u16* __restrict__ Wkb, const u16* __restrict__ Wvb,
    const float* __restrict__ bq, const float* __restrict__ bk, const float* __restrict__ bv,
    u16* __restrict__ Qm, u16* __restrict__ Km, u16* __restrict__ VmT)
{
    __shared__ u16 Ash[2][128 * 64];
    __shared__ u16 Bsh[2][64 * 64];
    const u16* A; const u16* W; const float* bias; float bscale; int z = blockIdx.z;
    if (z == 0)      { A = lnQ; W = Wqb; bias = bq; bscale = 0.125f; }
    else if (z == 1) { A = lnK; W = Wkb; bias = bk; bscale = 1.f; }
    else             { A = lnV; W = Wvb; bias = bv; bscale = 1.f; }
    int n0 = blockIdx.x * 64, m0 = blockIdx.y * 128;
    int t = threadIdx.x, l = t & 63, quad = l >> 4, c16 = l & 15;
    int w = t >> 6;

    f32x4 acc[2][4];
    f32x4 zz = {0.f, 0.f, 0.f, 0.f};
#pragma unroll
    for (int mi = 0; mi < 2; mi++)
#pragma unroll
        for (int ni = 0; ni < 4; ni++) acc[mi][ni] = zz;

    // prologue: stage tile 0 into buffer 0
#pragma unroll
    for (int i = 0; i < 4; i++) {
        int ch = i * 256 + t;
        int r = ch >> 3, pc = ch & 7, jc = pc ^ (r & 7);
        async16(A + (size_t)(m0 + r) * DDIM + jc * 8, (char*)Ash[0] + ch * 16);
    }
#pragma unroll
    for (int i = 0; i < 2; i++) {
        int ch = i * 256 + t;
        int r = ch >> 3, pc = ch & 7, jc = pc ^ (r & 7);
        async16(W + (size_t)(n0 + r) * DDIM + jc * 8, (char*)Bsh[0] + ch * 16);
    }
    for (int kt = 0; kt < 12; kt++) {
        int cur = kt & 1;
        __syncthreads();
        if (kt < 11) {
            int k0 = (kt + 1) * 64;
#pragma unroll
            for (int i = 0; i < 4; i++) {
                int ch = i * 256 + t;
                int r = ch >> 3, pc = ch & 7, jc = pc ^ (r & 7);
                async16(A + (size_t)(m0 + r) * DDIM + k0 + jc * 8, (char*)Ash[cur ^ 1] + ch * 16);
            }
#pragma unroll
            for (int i = 0; i < 2; i++) {
                int ch = i * 256 + t;
                int r = ch >> 3, pc = ch & 7, jc = pc ^ (r & 7);
                async16(W + (size_t)(n0 + r) * DDIM + k0 + jc * 8, (char*)Bsh[cur ^ 1] + ch * 16);
            }
        }
#pragma unroll
        for (int kk = 0; kk < 2; kk++) {
            bf16x8 a[2], b[4];
#pragma unroll
            for (int mi = 0; mi < 2; mi++) {
                int row = w * 32 + mi * 16 + c16;
                int p = (kk * 4 + quad) ^ (row & 7);
                a[mi] = *(const bf16x8*)(Ash[cur] + row * 64 + p * 8);
            }
#pragma unroll
            for (int ni = 0; ni < 4; ni++) {
                int row = ni * 16 + c16;
                int p = (kk * 4 + quad) ^ (row & 7);
                b[ni] = *(const bf16x8*)(Bsh[cur] + row * 64 + p * 8);
            }
#pragma unroll
            for (int mi = 0; mi < 2; mi++)
#pragma unroll
                for (int ni = 0; ni < 4; ni++)
                    acc[mi][ni] = __builtin_amdgcn_mfma_f32_16x16x32_bf16(a[mi], b[ni], acc[mi][ni], 0, 0, 0);
        }
        __syncthreads();
    }
    if (z < 2) {
        u16* out = (z == 0) ? Qm : Km;
        int Mact = (z == 0) ? NQ : SREAL;
#pragma unroll
        for (int mi = 0; mi < 2; mi++)
#pragma unroll
            for (int ni = 0; ni < 4; ni++) {
                int n = n0 + ni * 16 + c16;
                float bval = bias[n] * bscale;
#pragma unroll
                for (int r = 0; r < 4; r++) {
                    int m = m0 + w * 32 + mi * 16 + quad * 4 + r;
                    float val = (m < Mact) ? (acc[mi][ni][r] + bval) : 0.f;
                    out[(size_t)m * DDIM + n] = f2bf(val);
                }
            }
    } else {
        // V: write transposed [n (768)][m (2048)], zero pad rows m>=2000
#pragma unroll
        for (int mi = 0; mi < 2; mi++)
#pragma unroll
            for (int ni = 0; ni < 4; ni++) {
                int n = n0 + ni * 16 + c16;
                float bval = bias[n];
                int mbase = m0 + w * 32 + mi * 16 + quad * 4;
                ushort4 o;
                o.x = (mbase + 0 < SREAL) ? f2bf(acc[mi][ni][0] + bval) : (u16)0;
                o.y = (mbase + 1 < SREAL) ? f2bf(acc[mi][ni][1] + bval) : (u16)0;
                o.z = (mbase + 2 < SREAL) ? f2bf(acc[mi][ni][2] + bval) : (u16)0;
                o.w = (mbase + 3 < SREAL) ? f2bf(acc[mi][ni][3] + bval) : (u16)0;
                *(ushort4*)(VmT + (size_t)n * SPAD + mbase) = o;
            }
    }
}

// ---------------- split-S flash attention, no-max softmax, 64-s chunks ----------------
// 1536 blocks, XCD-swizzled; LDS 24.8KB -> 6 blocks/CU resident (grid exactly 6/CU).
__global__ __launch_bounds__(256, 4) void attn_kernel(
    const u16* __restrict__ Qm, const u16* __restrict__ Km, const u16* __restrict__ VmT,
    const int* __restrict__ bank_mask,
    u16* __restrict__ Opart, float* __restrict__ Lpart)
{
    __shared__ __align__(16) u16 SH[64 * 64 * 3];   // K | V^T | P
    __shared__ float mk[64];
    u16* Ksh = SH;
    u16* Vsh = SH + 4096;
    u16* Psh = SH + 8192;
    int b = blockIdx.x;
    int xcd = b & 7, j = b >> 3;
    int grp = xcd * 6 + (j >> 5);         // grp = sp*NHEAD + h  (48 groups)
    int qt = j & 31;
    int sp = grp / NHEAD, h = grp - sp * NHEAD;
    int q0 = qt * 64;
    int t = threadIdx.x, w = t >> 6, l = t & 63, quad = l >> 4, c16 = l & 15;

    bf16x8 qf[2];
#pragma unroll
    for (int kk = 0; kk < 2; kk++) {
        int row = q0 + w * 16 + c16;
        qf[kk] = *(const bf16x8*)(Qm + (size_t)row * DDIM + h * EDIM + kk * 32 + quad * 8);
    }
    bf16x8 ones;
#pragma unroll
    for (int i = 0; i < 8; i++) ones[i] = (__bf16)1.0f;

    f32x4 zz = {0.f, 0.f, 0.f, 0.f};
    f32x4 of[4], ol;
#pragma unroll
    for (int nei = 0; nei < 4; nei++) of[nei] = zz;
    ol = zz;

    for (int sc = 0; sc < 8; sc++) {
        int s0 = sp * 512 + sc * 64;
        // stage K [64 s][64 e] swizzled (512 x 16B chunks)
#pragma unroll
        for (int i = 0; i < 2; i++) {
            int ch = i * 256 + t;
            int r = ch >> 3, pc = ch & 7, jc = pc ^ (r & 7);
            async16(Km + (size_t)(s0 + r) * DDIM + h * EDIM + jc * 8, (char*)Ksh + ch * 16);
        }
        // stage V^T [64 e][64 s] swizzled
#pragma unroll
        for (int i = 0; i < 2; i++) {
            int ch = i * 256 + t;
            int e = ch >> 3, pc = ch & 7, jc = pc ^ (e & 7);
            async16(VmT + (size_t)(h * EDIM + e) * SPAD + s0 + jc * 8, (char*)Vsh + ch * 16);
        }
        if (t < 64) {
            int s = s0 + t;
            mk[t] = (s < SREAL && bank_mask[s] != 0) ? 1.f : 0.f;
        }
        __syncthreads();

        // QK^T (scale folded into Wq): 16 q-rows x 64 s-cols per wave
        f32x4 sacc[4];
#pragma unroll
        for (int ni = 0; ni < 4; ni++) sacc[ni] = zz;
#pragma unroll
        for (int kk = 0; kk < 2; kk++) {
            bf16x8 kb[4];
#pragma unroll
            for (int ni = 0; ni < 4; ni++) {
                int row = ni * 16 + c16;
                int p = (kk * 4 + quad) ^ (row & 7);
                kb[ni] = *(const bf16x8*)(Ksh + row * 64 + p * 8);
            }
#pragma unroll
            for (int ni = 0; ni < 4; ni++)
                sacc[ni] = __builtin_amdgcn_mfma_f32_16x16x32_bf16(qf[kk], kb[ni], sacc[ni], 0, 0, 0);
        }
        float m01[4];
#pragma unroll
        for (int ni = 0; ni < 4; ni++) m01[ni] = mk[ni * 16 + c16];
#pragma unroll
        for (int ni = 0; ni < 4; ni++)
#pragma unroll
            for (int r = 0; r < 4; r++)
                sacc[ni][r] = __expf(sacc[ni][r]) * m01[ni];

        // write P into own wave's rows of Psh (no barrier needed)
#pragma unroll
        for (int ni = 0; ni < 4; ni++)
#pragma unroll
            for (int r = 0; r < 4; r++) {
                int row = w * 16 + quad * 4 + r;
                int col = ni * 16 + c16;
                int p = (col >> 3) ^ (row & 7);
                Psh[row * 64 + p * 8 + (col & 7)] = f2bf(sacc[ni][r]);
            }

        // O += P @ V, l += P @ 1
#pragma unroll
        for (int kk = 0; kk < 2; kk++) {
            bf16x8 pa, vb[4];
            {
                int row = w * 16 + c16;
                int p = (kk * 4 + quad) ^ (row & 7);
                pa = *(const bf16x8*)(Psh + row * 64 + p * 8);
            }
#pragma unroll
            for (int nei = 0; nei < 4; nei++) {
                int e = nei * 16 + c16;
                int p = (kk * 4 + quad) ^ (e & 7);
                vb[nei] = *(const bf16x8*)(Vsh + e * 64 + p * 8);
            }
#pragma unroll
            for (int nei = 0; nei < 4; nei++)
                of[nei] = __builtin_amdgcn_mfma_f32_16x16x32_bf16(pa, vb[nei], of[nei], 0, 0, 0);
            ol = __builtin_amdgcn_mfma_f32_16x16x32_bf16(pa, ones, ol, 0, 0, 0);
        }
        __syncthreads();   // K/V/(P) reads done before next chunk staging
    }

    // epilogue: transpose O through LDS (per-wave slice), store coalesced bf16
    float* Ost = (float*)SH + w * (16 * 68);
#pragma unroll
    for (int nei = 0; nei < 4; nei++)
#pragma unroll
        for (int r = 0; r < 4; r++)
            Ost[(quad * 4 + r) * 68 + nei * 16 + c16] = of[nei][r];
    int qq = l >> 2, cc = (l & 3) ^ (qq & 3);
    int base = grp * 32 + qt;
    uint4 packed[2];
    u16* pk = (u16*)packed;
#pragma unroll
    for (int jj = 0; jj < 4; jj++) {
        f32x4 v = *(const f32x4*)(Ost + qq * 68 + cc * 16 + jj * 4);
        pk[jj * 4 + 0] = f2bf(v[0]); pk[jj * 4 + 1] = f2bf(v[1]);
        pk[jj * 4 + 2] = f2bf(v[2]); pk[jj * 4 + 3] = f2bf(v[3]);
    }
    {
        u16* dst = Opart + (size_t)base * 4096 + (w * 16 + qq) * 64 + cc * 16;
        *(uint4*)dst = packed[0];
        *(uint4*)(dst + 8) = packed[1];
    }
    if (c16 == 0) {
#pragma unroll
        for (int r = 0; r < 4; r++) {
            int rin = w * 16 + quad * 4 + r;
            Lpart[(size_t)base * 64 + rin] = ol[r];
        }
    }
}

// ---------------- combine partials + mean-pool over TQ; also init y with bias ----------------
__global__ __launch_bounds__(256) void combine_kernel(
    const u16* __restrict__ Opart, const float* __restrict__ Lpart,
    const float* __restrict__ bo, float* __restrict__ pooled, float* __restrict__ y)
{
    int tid = blockIdx.x * 256 + threadIdx.x;
    if (tid < 49152) {
        int c4 = tid % 192;
        ((f32x4*)y)[tid] = ((const f32x4*)bo)[c4];
    }
    int gi = blockIdx.x * 4 + (threadIdx.x >> 6);   // 0..3071
    int e = threadIdx.x & 63;
    int lq = gi / NHEAD, h = gi - lq * NHEAD;
    float acc = 0.f;
#pragma unroll
    for (int row = 0; row < 8; row++) {
        int qrow = lq * 8 + row;
        int qt = qrow >> 6, rin = qrow & 63;
        float Ls = 0.f, val = 0.f;
#pragma unroll
        for (int sp = 0; sp < NSPLIT; sp++) {
            int base = (sp * NHEAD + h) * 32 + qt;
            Ls += Lpart[(size_t)base * 64 + rin];
            val += bf2f(Opart[(size_t)base * 4096 + rin * 64 + e]);
        }
        acc += val / Ls;
    }
    pooled[(size_t)lq * DDIM + h * EDIM + e] = acc * 0.125f;
}

// ---------------- final fp32 GEMM y += pooled(256,768) @ Wo(768,768)^T, 576 blocks ----------------
__global__ __launch_bounds__(256) void wo_kernel(
    const float* __restrict__ pooled, const float* __restrict__ Wo, float* __restrict__ y)
{
    __shared__ float As[32 * 132];
    int m0 = blockIdx.x * 32, n0 = blockIdx.y * 64, k0 = blockIdx.z * 128;
    int t = threadIdx.x;
#pragma unroll
    for (int i = 0; i < 4; i++) {
        int f = i * 256 + t;        // 1024 float4s = 32 rows x 32 f4
        int r = f >> 5, c4 = f & 31;
        f32x4 v = *(const f32x4*)(pooled + (size_t)(m0 + r) * DDIM + k0 + c4 * 4);
        *(f32x4*)(As + r * 132 + c4 * 4) = v;
    }
    __syncthreads();
    int tx = t & 15, my = t >> 4;   // tx: 4 n-cols, my: 2 m-rows
    float acc[2][4];
#pragma unroll
    for (int r = 0; r < 2; r++)
#pragma unroll
        for (int jc = 0; jc < 4; jc++) acc[r][jc] = 0.f;
    for (int kq = 0; kq < 32; kq++) {
        f32x4 bj[4];
#pragma unroll
        for (int jc = 0; jc < 4; jc++)
            bj[jc] = *(const f32x4*)(Wo + (size_t)(n0 + tx * 4 + jc) * DDIM + k0 + kq * 4);
        f32x4 a4[2];
#pragma unroll
        for (int r = 0; r < 2; r++)
            a4[r] = *(const f32x4*)(As + (my * 2 + r) * 132 + kq * 4);
#pragma unroll
        for (int jj = 0; jj < 4; jj++)
#pragma unroll
            for (int r = 0; r < 2; r++)
#pragma unroll
                for (int jc = 0; jc < 4; jc++) acc[r][jc] += a4[r][jj] * bj[jc][jj];
    }
#pragma unroll
    for (int r = 0; r < 2; r++)
#pragma unroll
        for (int jc = 0; jc < 4; jc++)
            atomicAdd(&y[(size_t)(m0 + my * 2 + r) * DDIM + n0 + tx * 4 + jc], acc[r][jc]);
}

extern "C" void kernel_launch(void* const* d_in, const int* in_sizes, int n_in,
                              void* d_out, int out_size, void* d_ws, size_t ws_size,
                              hipStream_t stream)
{
    const float* tgt     = (const float*)d_in[0];
    const float* keyb    = (const float*)d_in[1];
    const float* valb    = (const float*)d_in[2];
    const int*   mask    = (const int*)d_in[3];
    const float* Wq      = (const float*)d_in[4];
    const float* bq      = (const float*)d_in[5];
    const float* Wk      = (const float*)d_in[6];
    const float* bk      = (const float*)d_in[7];
    const float* Wv      = (const float*)d_in[8];
    const float* bv      = (const float*)d_in[9];
    const float* Wo      = (const float*)d_in[10];
    const float* bo      = (const float*)d_in[11];
    const float* g_q     = (const float*)d_in[12];
    const float* beta_q  = (const float*)d_in[13];
    const float* g_kv    = (const float*)d_in[14];
    const float* beta_kv = (const float*)d_in[15];
    float* y = (float*)d_out;

    char* ws = (char*)d_ws;
    // persistent:
    u16* Qm  = (u16*)(ws + 0);
    u16* Km  = (u16*)(ws + 3145728);
    u16* VmT = (u16*)(ws + 6291456);
    // phase A (dead after proj_kernel):
    u16* lnQ = (u16*)(ws + 9437184);
    u16* lnK = (u16*)(ws + 12582912);
    u16* lnV = (u16*)(ws + 15728640);
    u16* Wqb = (u16*)(ws + 18874368);
    u16* Wkb = (u16*)(ws + 20054016);
    u16* Wvb = (u16*)(ws + 21233664);
    // phase B (aliases phase A region):
    u16*   Opart  = (u16*)(ws + 9437184);     // 1536*4096*2 = 12.58 MB
    float* Lpart  = (float*)(ws + 34603008);  // 393,216
    float* pooled = (float*)(ws + 34996224);  // 786,432

    hipLaunchKernelGGL(prep_kernel, dim3(3264), dim3(256), 0, stream,
                       Wq, Wk, Wv, Wqb, Wkb, Wvb,
                       tgt, keyb, valb, g_q, beta_q, g_kv, beta_kv, lnQ, lnK, lnV);
    hipLaunchKernelGGL(proj_kernel, dim3(12, 16, 3), dim3(256), 0, stream,
                       lnQ, lnK, lnV, Wqb, Wkb, Wvb, bq, bk, bv, Qm, Km, VmT);
    hipLaunchKernelGGL(attn_kernel, dim3(1536), dim3(256), 0, stream,
                       Qm, Km, VmT, mask, Opart, Lpart);
    hipLaunchKernelGGL(combine_kernel, dim3(768), dim3(256), 0, stream,
                       Opart, Lpart, bo, pooled, y);
    hipLaunchKernelGGL(wo_kernel, dim3(8, 12, 6), dim3(256), 0, stream,
                       pooled, Wo, y);
}

// Round 5
// 159.343 us; speedup vs baseline: 1.6024x; 1.2645x over previous
//
#include <hip/hip_runtime.h>
#include <stdint.h>

typedef unsigned short u16;
typedef float f32x4 __attribute__((ext_vector_type(4)));
typedef __bf16 bf16x8 __attribute__((ext_vector_type(8)));

#define DDIM 768
#define NHEAD 12
#define EDIM 64
#define SREAL 2000
#define SPAD 2048
#define NQ 2048
#define NSPLIT 4

__device__ __forceinline__ u16 f2bf(float f) {
    unsigned u = __float_as_uint(f);
    return (u16)((u + 0x7fffu + ((u >> 16) & 1u)) >> 16);
}
__device__ __forceinline__ float bf2f(u16 v) {
    return __uint_as_float(((unsigned)v) << 16);
}

__device__ __forceinline__ void async16(const void* g, void* l) {
    __builtin_amdgcn_global_load_lds(
        (const __attribute__((address_space(1))) void*)(const void*)g,
        (__attribute__((address_space(3))) void*)l, 16, 0, 0);
}

// ---------------- fused: cast weights -> bf16 (Wq pre-scaled by 0.125, incl. Wo) + layernorm ----------------
__global__ __launch_bounds__(256) void prep_kernel(
    const float* __restrict__ Wq, const float* __restrict__ Wk, const float* __restrict__ Wv,
    const float* __restrict__ Wo,
    u16* __restrict__ Wqb, u16* __restrict__ Wkb, u16* __restrict__ Wvb, u16* __restrict__ Wob,
    const float* __restrict__ tgt, const float* __restrict__ keyb, const float* __restrict__ valb,
    const float* __restrict__ g_q, const float* __restrict__ b_q,
    const float* __restrict__ g_kv, const float* __restrict__ b_kv,
    u16* __restrict__ lnQ, u16* __restrict__ lnK, u16* __restrict__ lnV)
{
    int bx = blockIdx.x;
    if (bx < 2304) {
        int g = bx * 256 + threadIdx.x;   // float4 index, total 4*147456
        const float* src; u16* dst; int idx; float sc = 1.f;
        if (g < 147456)      { src = Wq; dst = Wqb; idx = g; sc = 0.125f; }
        else if (g < 294912) { src = Wk; dst = Wkb; idx = g - 147456; }
        else if (g < 442368) { src = Wv; dst = Wvb; idx = g - 294912; }
        else                 { src = Wo; dst = Wob; idx = g - 442368; }
        f32x4 a = ((const f32x4*)src)[idx];
        ushort4 o;
        o.x = f2bf(a[0] * sc); o.y = f2bf(a[1] * sc);
        o.z = f2bf(a[2] * sc); o.w = f2bf(a[3] * sc);
        ((ushort4*)dst)[idx] = o;
        return;
    }
    int row = (bx - 2304) * 4 + (threadIdx.x >> 6);
    int l = threadIdx.x & 63;
    const float* src = nullptr; const float* gg; const float* bb; u16* dst;
    bool zero = false;
    if (row < 2048) {
        src = tgt + (size_t)row * DDIM; gg = g_q; bb = b_q; dst = lnQ + (size_t)row * DDIM;
    } else if (row < 4096) {
        int r = row - 2048; gg = g_kv; bb = b_kv; dst = lnK + (size_t)r * DDIM;
        if (r < SREAL) src = keyb + (size_t)r * DDIM; else zero = true;
    } else {
        int r = row - 4096; gg = g_kv; bb = b_kv; dst = lnV + (size_t)r * DDIM;
        if (r < SREAL) src = valb + (size_t)r * DDIM; else zero = true;
    }
    if (zero) {
        ushort4 z; z.x = 0; z.y = 0; z.z = 0; z.w = 0;
#pragma unroll
        for (int i = 0; i < 3; i++) ((ushort4*)dst)[l + 64 * i] = z;
        return;
    }
    f32x4 a[3];
#pragma unroll
    for (int i = 0; i < 3; i++) a[i] = ((const f32x4*)src)[l + 64 * i];
    float s = 0.f;
#pragma unroll
    for (int i = 0; i < 3; i++) { s += a[i][0] + a[i][1] + a[i][2] + a[i][3]; }
#pragma unroll
    for (int m = 1; m < 64; m <<= 1) s += __shfl_xor(s, m, 64);
    float mean = s * (1.f / 768.f);
    float v = 0.f;
#pragma unroll
    for (int i = 0; i < 3; i++)
#pragma unroll
        for (int j = 0; j < 4; j++) { float d = a[i][j] - mean; v += d * d; }
#pragma unroll
    for (int m = 1; m < 64; m <<= 1) v += __shfl_xor(v, m, 64);
    float rstd = rsqrtf(v * (1.f / 768.f) + 1e-5f);
#pragma unroll
    for (int i = 0; i < 3; i++) {
        f32x4 g4 = ((const f32x4*)gg)[l + 64 * i];
        f32x4 b4 = ((const f32x4*)bb)[l + 64 * i];
        ushort4 o;
        o.x = f2bf((a[i][0] - mean) * rstd * g4[0] + b4[0]);
        o.y = f2bf((a[i][1] - mean) * rstd * g4[1] + b4[1]);
        o.z = f2bf((a[i][2] - mean) * rstd * g4[2] + b4[2]);
        o.w = f2bf((a[i][3] - mean) * rstd * g4[3] + b4[3]);
        ((ushort4*)dst)[l + 64 * i] = o;
    }
}

// ---------------- batched projection GEMM: C = A(M,768) @ W(768,768)^T + bias ----------------
// 128m x 64n tile, BK=64 double-buffered, 576 blocks (2.25/CU).
__global__ __launch_bounds__(256) void proj_kernel(
    const u16* __restrict__ lnQ, const u16* __restrict__ lnK, const u16* __restrict__ lnV,
    const u16* __restrict__ Wqb, const u16* __restrict__ Wkb, const u16* __restrict__ Wvb,
    const float* __restrict__ bq, const float* __restrict__ bk, const float* __restrict__ bv,
    u16* __restrict__ Qm, u16* __restrict__ Km, u16* __restrict__ VmT)
{
    __shared__ u16 Ash[2][128 * 64];
    __shared__ u16 Bsh[2][64 * 64];
    const u16* A; const u16* W; const float* bias; float bscale; int z = blockIdx.z;
    if (z == 0)      { A = lnQ; W = Wqb; bias = bq; bscale = 0.125f; }
    else if (z == 1) { A = lnK; W = Wkb; bias = bk; bscale = 1.f; }
    else             { A = lnV; W = Wvb; bias = bv; bscale = 1.f; }
    int n0 = blockIdx.x * 64, m0 = blockIdx.y * 128;
    int t = threadIdx.x, l = t & 63, quad = l >> 4, c16 = l & 15;
    int w = t >> 6;

    f32x4 acc[2][4];
    f32x4 zz = {0.f, 0.f, 0.f, 0.f};
#pragma unroll
    for (int mi = 0; mi < 2; mi++)
#pragma unroll
        for (int ni = 0; ni < 4; ni++) acc[mi][ni] = zz;

#pragma unroll
    for (int i = 0; i < 4; i++) {
        int ch = i * 256 + t;
        int r = ch >> 3, pc = ch & 7, jc = pc ^ (r & 7);
        async16(A + (size_t)(m0 + r) * DDIM + jc * 8, (char*)Ash[0] + ch * 16);
    }
#pragma unroll
    for (int i = 0; i < 2; i++) {
        int ch = i * 256 + t;
        int r = ch >> 3, pc = ch & 7, jc = pc ^ (r & 7);
        async16(W + (size_t)(n0 + r) * DDIM + jc * 8, (char*)Bsh[0] + ch * 16);
    }
    for (int kt = 0; kt < 12; kt++) {
        int cur = kt & 1;
        __syncthreads();
        if (kt < 11) {
            int k0 = (kt + 1) * 64;
#pragma unroll
            for (int i = 0; i < 4; i++) {
                int ch = i * 256 + t;
                int r = ch >> 3, pc = ch & 7, jc = pc ^ (r & 7);
                async16(A + (size_t)(m0 + r) * DDIM + k0 + jc * 8, (char*)Ash[cur ^ 1] + ch * 16);
            }
#pragma unroll
            for (int i = 0; i < 2; i++) {
                int ch = i * 256 + t;
                int r = ch >> 3, pc = ch & 7, jc = pc ^ (r & 7);
                async16(W + (size_t)(n0 + r) * DDIM + k0 + jc * 8, (char*)Bsh[cur ^ 1] + ch * 16);
            }
        }
#pragma unroll
        for (int kk = 0; kk < 2; kk++) {
            bf16x8 a[2], b[4];
#pragma unroll
            for (int mi = 0; mi < 2; mi++) {
                int row = w * 32 + mi * 16 + c16;
                int p = (kk * 4 + quad) ^ (row & 7);
                a[mi] = *(const bf16x8*)(Ash[cur] + row * 64 + p * 8);
            }
#pragma unroll
            for (int ni = 0; ni < 4; ni++) {
                int row = ni * 16 + c16;
                int p = (kk * 4 + quad) ^ (row & 7);
                b[ni] = *(const bf16x8*)(Bsh[cur] + row * 64 + p * 8);
            }
#pragma unroll
            for (int mi = 0; mi < 2; mi++)
#pragma unroll
                for (int ni = 0; ni < 4; ni++)
                    acc[mi][ni] = __builtin_amdgcn_mfma_f32_16x16x32_bf16(a[mi], b[ni], acc[mi][ni], 0, 0, 0);
        }
        __syncthreads();
    }
    if (z < 2) {
        u16* out = (z == 0) ? Qm : Km;
        int Mact = (z == 0) ? NQ : SREAL;
#pragma unroll
        for (int mi = 0; mi < 2; mi++)
#pragma unroll
            for (int ni = 0; ni < 4; ni++) {
                int n = n0 + ni * 16 + c16;
                float bval = bias[n] * bscale;
#pragma unroll
                for (int r = 0; r < 4; r++) {
                    int m = m0 + w * 32 + mi * 16 + quad * 4 + r;
                    float val = (m < Mact) ? (acc[mi][ni][r] + bval) : 0.f;
                    out[(size_t)m * DDIM + n] = f2bf(val);
                }
            }
    } else {
#pragma unroll
        for (int mi = 0; mi < 2; mi++)
#pragma unroll
            for (int ni = 0; ni < 4; ni++) {
                int n = n0 + ni * 16 + c16;
                float bval = bias[n];
                int mbase = m0 + w * 32 + mi * 16 + quad * 4;
                ushort4 o;
                o.x = (mbase + 0 < SREAL) ? f2bf(acc[mi][ni][0] + bval) : (u16)0;
                o.y = (mbase + 1 < SREAL) ? f2bf(acc[mi][ni][1] + bval) : (u16)0;
                o.z = (mbase + 2 < SREAL) ? f2bf(acc[mi][ni][2] + bval) : (u16)0;
                o.w = (mbase + 3 < SREAL) ? f2bf(acc[mi][ni][3] + bval) : (u16)0;
                *(ushort4*)(VmT + (size_t)n * SPAD + mbase) = o;
            }
    }
}

// ---------------- split-S flash attention, no-max softmax, 64-s chunks ----------------
__global__ __launch_bounds__(256, 4) void attn_kernel(
    const u16* __restrict__ Qm, const u16* __restrict__ Km, const u16* __restrict__ VmT,
    const int* __restrict__ bank_mask,
    u16* __restrict__ Opart, float* __restrict__ Lpart)
{
    __shared__ __align__(16) u16 SH[64 * 64 * 3];   // K | V^T | P
    __shared__ float mk[64];
    u16* Ksh = SH;
    u16* Vsh = SH + 4096;
    u16* Psh = SH + 8192;
    int b = blockIdx.x;
    int xcd = b & 7, j = b >> 3;
    int grp = xcd * 6 + (j >> 5);         // grp = sp*NHEAD + h
    int qt = j & 31;
    int sp = grp / NHEAD, h = grp - sp * NHEAD;
    int q0 = qt * 64;
    int t = threadIdx.x, w = t >> 6, l = t & 63, quad = l >> 4, c16 = l & 15;

    bf16x8 qf[2];
#pragma unroll
    for (int kk = 0; kk < 2; kk++) {
        int row = q0 + w * 16 + c16;
        qf[kk] = *(const bf16x8*)(Qm + (size_t)row * DDIM + h * EDIM + kk * 32 + quad * 8);
    }
    bf16x8 ones;
#pragma unroll
    for (int i = 0; i < 8; i++) ones[i] = (__bf16)1.0f;

    f32x4 zz = {0.f, 0.f, 0.f, 0.f};
    f32x4 of[4], ol;
#pragma unroll
    for (int nei = 0; nei < 4; nei++) of[nei] = zz;
    ol = zz;

    for (int sc = 0; sc < 8; sc++) {
        int s0 = sp * 512 + sc * 64;
#pragma unroll
        for (int i = 0; i < 2; i++) {
            int ch = i * 256 + t;
            int r = ch >> 3, pc = ch & 7, jc = pc ^ (r & 7);
            async16(Km + (size_t)(s0 + r) * DDIM + h * EDIM + jc * 8, (char*)Ksh + ch * 16);
        }
#pragma unroll
        for (int i = 0; i < 2; i++) {
            int ch = i * 256 + t;
            int e = ch >> 3, pc = ch & 7, jc = pc ^ (e & 7);
            async16(VmT + (size_t)(h * EDIM + e) * SPAD + s0 + jc * 8, (char*)Vsh + ch * 16);
        }
        if (t < 64) {
            int s = s0 + t;
            mk[t] = (s < SREAL && bank_mask[s] != 0) ? 1.f : 0.f;
        }
        __syncthreads();

        f32x4 sacc[4];
#pragma unroll
        for (int ni = 0; ni < 4; ni++) sacc[ni] = zz;
#pragma unroll
        for (int kk = 0; kk < 2; kk++) {
            bf16x8 kb[4];
#pragma unroll
            for (int ni = 0; ni < 4; ni++) {
                int row = ni * 16 + c16;
                int p = (kk * 4 + quad) ^ (row & 7);
                kb[ni] = *(const bf16x8*)(Ksh + row * 64 + p * 8);
            }
#pragma unroll
            for (int ni = 0; ni < 4; ni++)
                sacc[ni] = __builtin_amdgcn_mfma_f32_16x16x32_bf16(qf[kk], kb[ni], sacc[ni], 0, 0, 0);
        }
        float m01[4];
#pragma unroll
        for (int ni = 0; ni < 4; ni++) m01[ni] = mk[ni * 16 + c16];
#pragma unroll
        for (int ni = 0; ni < 4; ni++)
#pragma unroll
            for (int r = 0; r < 4; r++)
                sacc[ni][r] = __expf(sacc[ni][r]) * m01[ni];

#pragma unroll
        for (int ni = 0; ni < 4; ni++)
#pragma unroll
            for (int r = 0; r < 4; r++) {
                int row = w * 16 + quad * 4 + r;
                int col = ni * 16 + c16;
                int p = (col >> 3) ^ (row & 7);
                Psh[row * 64 + p * 8 + (col & 7)] = f2bf(sacc[ni][r]);
            }

#pragma unroll
        for (int kk = 0; kk < 2; kk++) {
            bf16x8 pa, vb[4];
            {
                int row = w * 16 + c16;
                int p = (kk * 4 + quad) ^ (row & 7);
                pa = *(const bf16x8*)(Psh + row * 64 + p * 8);
            }
#pragma unroll
            for (int nei = 0; nei < 4; nei++) {
                int e = nei * 16 + c16;
                int p = (kk * 4 + quad) ^ (e & 7);
                vb[nei] = *(const bf16x8*)(Vsh + e * 64 + p * 8);
            }
#pragma unroll
            for (int nei = 0; nei < 4; nei++)
                of[nei] = __builtin_amdgcn_mfma_f32_16x16x32_bf16(pa, vb[nei], of[nei], 0, 0, 0);
            ol = __builtin_amdgcn_mfma_f32_16x16x32_bf16(pa, ones, ol, 0, 0, 0);
        }
        __syncthreads();
    }

    // epilogue: transpose O through LDS (per-wave slice), store coalesced bf16
    float* Ost = (float*)SH + w * (16 * 68);
#pragma unroll
    for (int nei = 0; nei < 4; nei++)
#pragma unroll
        for (int r = 0; r < 4; r++)
            Ost[(quad * 4 + r) * 68 + nei * 16 + c16] = of[nei][r];
    int qq = l >> 2, cc = (l & 3) ^ (qq & 3);
    int base = grp * 32 + qt;
    uint4 packed[2];
    u16* pk = (u16*)packed;
#pragma unroll
    for (int jj = 0; jj < 4; jj++) {
        f32x4 v = *(const f32x4*)(Ost + qq * 68 + cc * 16 + jj * 4);
        pk[jj * 4 + 0] = f2bf(v[0]); pk[jj * 4 + 1] = f2bf(v[1]);
        pk[jj * 4 + 2] = f2bf(v[2]); pk[jj * 4 + 3] = f2bf(v[3]);
    }
    {
        u16* dst = Opart + (size_t)base * 4096 + (w * 16 + qq) * 64 + cc * 16;
        *(uint4*)dst = packed[0];
        *(uint4*)(dst + 8) = packed[1];
    }
    if (c16 == 0) {
#pragma unroll
        for (int r = 0; r < 4; r++) {
            int rin = w * 16 + quad * 4 + r;
            Lpart[(size_t)base * 64 + rin] = ol[r];
        }
    }
}

// ---------------- combine partials + mean-pool over TQ -> pooled (bf16) ----------------
__global__ __launch_bounds__(256) void combine_kernel(
    const u16* __restrict__ Opart, const float* __restrict__ Lpart,
    u16* __restrict__ pooledb)
{
    int gi = blockIdx.x * 4 + (threadIdx.x >> 6);   // 0..3071
    int e = threadIdx.x & 63;
    int lq = gi / NHEAD, h = gi - lq * NHEAD;
    float acc = 0.f;
#pragma unroll
    for (int row = 0; row < 8; row++) {
        int qrow = lq * 8 + row;
        int qt = qrow >> 6, rin = qrow & 63;
        float Ls = 0.f, val = 0.f;
#pragma unroll
        for (int sp = 0; sp < NSPLIT; sp++) {
            int base = (sp * NHEAD + h) * 32 + qt;
            Ls += Lpart[(size_t)base * 64 + rin];
            val += bf2f(Opart[(size_t)base * 4096 + rin * 64 + e]);
        }
        acc += val / Ls;
    }
    pooledb[(size_t)lq * DDIM + h * EDIM + e] = f2bf(acc * 0.125f);
}

// ---------------- final GEMM y = pooled(256,768) @ Wo(768,768)^T + bo, bf16 MFMA ----------------
// 64m x 64n tiles, BK=128, grid (4,12)=48 blocks. No atomics; y written exactly once.
__global__ __launch_bounds__(256) void wo_kernel(
    const u16* __restrict__ pb, const u16* __restrict__ Wob,
    const float* __restrict__ bo, float* __restrict__ y)
{
    __shared__ u16 Ash[64 * 128];
    __shared__ u16 Bsh[64 * 128];
    int m0 = blockIdx.x * 64, n0 = blockIdx.y * 64;
    int t = threadIdx.x, w = t >> 6, l = t & 63, quad = l >> 4, c16 = l & 15;

    f32x4 acc[4];
    f32x4 zz = {0.f, 0.f, 0.f, 0.f};
#pragma unroll
    for (int ni = 0; ni < 4; ni++) acc[ni] = zz;

    for (int kt = 0; kt < 6; kt++) {
        int k0 = kt * 128;
#pragma unroll
        for (int i = 0; i < 4; i++) {
            int ch = i * 256 + t;
            int r = ch >> 4, pc = ch & 15, jc = pc ^ (r & 15);
            async16(pb + (size_t)(m0 + r) * DDIM + k0 + jc * 8, (char*)Ash + ch * 16);
            async16(Wob + (size_t)(n0 + r) * DDIM + k0 + jc * 8, (char*)Bsh + ch * 16);
        }
        __syncthreads();
#pragma unroll
        for (int kk = 0; kk < 4; kk++) {
            int p = (kk * 4 + quad) ^ c16;
            bf16x8 a = *(const bf16x8*)(Ash + (w * 16 + c16) * 128 + p * 8);
            bf16x8 b[4];
#pragma unroll
            for (int ni = 0; ni < 4; ni++)
                b[ni] = *(const bf16x8*)(Bsh + (ni * 16 + c16) * 128 + p * 8);
#pragma unroll
            for (int ni = 0; ni < 4; ni++)
                acc[ni] = __builtin_amdgcn_mfma_f32_16x16x32_bf16(a, b[ni], acc[ni], 0, 0, 0);
        }
        __syncthreads();
    }
#pragma unroll
    for (int ni = 0; ni < 4; ni++) {
        int n = n0 + ni * 16 + c16;
        float bval = bo[n];
#pragma unroll
        for (int r = 0; r < 4; r++) {
            int m = m0 + w * 16 + quad * 4 + r;
            y[(size_t)m * DDIM + n] = acc[ni][r] + bval;
        }
    }
}

extern "C" void kernel_launch(void* const* d_in, const int* in_sizes, int n_in,
                              void* d_out, int out_size, void* d_ws, size_t ws_size,
                              hipStream_t stream)
{
    const float* tgt     = (const float*)d_in[0];
    const float* keyb    = (const float*)d_in[1];
    const float* valb    = (const float*)d_in[2];
    const int*   mask    = (const int*)d_in[3];
    const float* Wq      = (const float*)d_in[4];
    const float* bq      = (const float*)d_in[5];
    const float* Wk      = (const float*)d_in[6];
    const float* bk      = (const float*)d_in[7];
    const float* Wv      = (const float*)d_in[8];
    const float* bv      = (const float*)d_in[9];
    const float* Wo      = (const float*)d_in[10];
    const float* bo      = (const float*)d_in[11];
    const float* g_q     = (const float*)d_in[12];
    const float* beta_q  = (const float*)d_in[13];
    const float* g_kv    = (const float*)d_in[14];
    const float* beta_kv = (const float*)d_in[15];
    float* y = (float*)d_out;

    char* ws = (char*)d_ws;
    // persistent:
    u16* Qm  = (u16*)(ws + 0);           // 3,145,728
    u16* Km  = (u16*)(ws + 3145728);     // 3,145,728
    u16* VmT = (u16*)(ws + 6291456);     // 3,145,728
    u16* Wob = (u16*)(ws + 9437184);     // 1,179,648
    // phase A (dead after proj_kernel):
    u16* lnQ = (u16*)(ws + 10616832);
    u16* lnK = (u16*)(ws + 13762560);
    u16* lnV = (u16*)(ws + 16908288);
    u16* Wqb = (u16*)(ws + 20054016);
    u16* Wkb = (u16*)(ws + 21233664);
    u16* Wvb = (u16*)(ws + 22413312);    // ends 23,592,960
    // phase B (aliases phase A region):
    u16*   Opart   = (u16*)(ws + 10616832);   // 12,582,912 -> ends 23,199,744
    float* Lpart   = (float*)(ws + 23592960); // 393,216
    u16*   pooledb = (u16*)(ws + 23986176);   // 393,216

    hipLaunchKernelGGL(prep_kernel, dim3(3840), dim3(256), 0, stream,
                       Wq, Wk, Wv, Wo, Wqb, Wkb, Wvb, Wob,
                       tgt, keyb, valb, g_q, beta_q, g_kv, beta_kv, lnQ, lnK, lnV);
    hipLaunchKernelGGL(proj_kernel, dim3(12, 16, 3), dim3(256), 0, stream,
                       lnQ, lnK, lnV, Wqb, Wkb, Wvb, bq, bk, bv, Qm, Km, VmT);
    hipLaunchKernelGGL(attn_kernel, dim3(1536), dim3(256), 0, stream,
                       Qm, Km, VmT, mask, Opart, Lpart);
    hipLaunchKernelGGL(combine_kernel, dim3(768), dim3(256), 0, stream,
                       Opart, Lpart, pooledb);
    hipLaunchKernelGGL(wo_kernel, dim3(4, 12), dim3(256), 0, stream,
                       pooledb, Wob, bo, y);
}